// Round 11
// baseline (282.945 us; speedup 1.0000x reference)
//
#include <hip/hip_runtime.h>
#include <math.h>

// ---------------------------------------------------------------------------
// RGAPConv, CSR-gather formulation (R18 = R17 with sort1 LDS staging
// restored — R17 post-mortem: removing it scattered ~800k 8B stores,
// ~8x write amplification, +10us total):
//   sort1:     edge tail fused + LDS-staged coarse scatter (37KB, coalesced
//              run copy) — the R16 form.
//   sort2:     single-pass: bucket entries cached in 24 unrolled registers
//              (grid-limited at 196 blocks, so VGPRs are free).
//   hscan2:    hred+hscan merged: 1 block x 1024 threads.
//   gather:    R16 lean loop (LDS (av,st) staging + relM linearity hoist).
//   edge1a:    rule-MLP (8 edges/thread) + dst>>8 histogram fused.
//   node:      MFMA bf16 GEMM (16x16x32), 128x128 tile.
//   alpha:     coalesced per-edge kernel from per-node {m, inv}.
// ---------------------------------------------------------------------------

using bf16x8 = __attribute__((ext_vector_type(8))) short;
using f32x4  = __attribute__((ext_vector_type(4))) float;

__device__ __forceinline__ float wave_max(float v) {
    #pragma unroll
    for (int o = 32; o > 0; o >>= 1) v = fmaxf(v, __shfl_xor(v, o, 64));
    return v;
}
__device__ __forceinline__ float wave_sum(float v) {
    #pragma unroll
    for (int o = 32; o > 0; o >>= 1) v += __shfl_xor(v, o, 64);
    return v;
}

__device__ __forceinline__ unsigned bf16rne(float f) {
    unsigned u = __float_as_uint(f);
    return (u + 0x7FFFu + ((u >> 16) & 1u)) >> 16;  // round-to-nearest-even
}
__device__ __forceinline__ float bflo(unsigned u) { return __uint_as_float(u << 16); }
__device__ __forceinline__ float bfhi(unsigned u) { return __uint_as_float(u & 0xFFFF0000u); }

// grid = 146 blocks x 128 threads. Builds all small tables.
// W2bT is stored TRANSPOSED: W2bT[n*128 + k] = (Wv@msg_w)[k][n] in bf16.
__global__ void __launch_bounds__(128) precompute_kernel(
    const float* __restrict__ Wq, const float* __restrict__ bq,
    const float* __restrict__ Wk, const float* __restrict__ bk,
    const float* __restrict__ Wv, const float* __restrict__ bv,
    const float* __restrict__ rel_emb, const float* __restrict__ attn_vec,
    const float* __restrict__ msg_w, const float* __restrict__ msg_b,
    const float* __restrict__ gnw, const float* __restrict__ grb,
    const float* __restrict__ gnb,
    const float* __restrict__ rule_w1, const float* __restrict__ rule_b1,
    const float* __restrict__ rule_w2,
    unsigned short* __restrict__ W2bT, float* __restrict__ c2,
    float* __restrict__ wkA, float* __restrict__ wqA,
    float* __restrict__ wkG, float* __restrict__ wqG,
    float* __restrict__ relA, float* __restrict__ relM,
    float* __restrict__ consts,
    float4* __restrict__ w1t, float2* __restrict__ w12)
{
    __shared__ float red[128];
    int bid = blockIdx.x, j = threadIdx.x;

    auto blk_reduce = [&](float v) -> float {
        red[j] = v;
        __syncthreads();
        for (int s = 64; s > 0; s >>= 1) {
            if (j < s) red[j] += red[j + s];
            __syncthreads();
        }
        float r = red[0];
        __syncthreads();
        return r;
    };

    if (bid < 128) {
        int i = bid;  // k index
        float acc = 0.f;
        #pragma unroll 8
        for (int k = 0; k < 128; ++k) acc = fmaf(Wv[i * 128 + k], msg_w[k * 128 + j], acc);
        W2bT[j * 128 + i] = (unsigned short)bf16rne(acc);  // transposed store
        float r;
        r = blk_reduce(Wk[i * 128 + j] * attn_vec[j]);        if (j == 0) wkA[i] = r;
        r = blk_reduce(Wq[i * 128 + j] * attn_vec[128 + j]);  if (j == 0) wqA[i] = r;
        r = blk_reduce(Wk[i * 128 + j] * gnw[j]);             if (j == 0) wkG[i] = r;
        r = blk_reduce(Wq[i * 128 + j] * gnw[128 + j]);       if (j == 0) wqG[i] = r;
    } else if (bid < 144) {
        int t = bid - 128;
        float acc = 0.f;
        #pragma unroll 8
        for (int k = 0; k < 128; ++k) acc = fmaf(rel_emb[t * 128 + k], msg_w[k * 128 + j], acc);
        relM[t * 128 + j] = acc;
        float r = blk_reduce(rel_emb[t * 128 + j] * attn_vec[256 + j]);
        if (j == 0) relA[t] = r;
    } else if (bid == 144) {
        float acc = msg_b[j];
        #pragma unroll 8
        for (int k = 0; k < 128; ++k) acc = fmaf(bv[k], msg_w[k * 128 + j], acc);
        c2[j] = acc;
        w1t[j] = make_float4(rule_w1[j], rule_w1[128 + j], rule_w1[256 + j], rule_w1[384 + j]);
        w12[j] = make_float2(rule_b1[j], rule_w2[j]);
    } else {
        float r = blk_reduce(bk[j] * attn_vec[j] + bq[j] * attn_vec[128 + j]);
        if (j == 0) consts[0] = r;
        r = blk_reduce(bk[j] * gnw[j] + bq[j] * gnw[128 + j]);
        if (j == 0) consts[1] = r + grb[0] + gnb[0];
    }
}

// MFMA node GEMM: 128x128 tile/block, 4 waves each own a 64x64 quadrant.
__global__ void __launch_bounds__(256) node_kernel(
    const float4* __restrict__ x4, const unsigned short* __restrict__ W2bT,
    const float* __restrict__ c2,
    const float* __restrict__ wkA, const float* __restrict__ wqA,
    const float* __restrict__ wkG, const float* __restrict__ wqG,
    unsigned* __restrict__ Vmb, float2* __restrict__ srcPack,
    float2* __restrict__ dstPack, int n_nodes)
{
    __shared__ unsigned short Asu[128][136];
    __shared__ unsigned short Bsu[128][136];
    const int tid = threadIdx.x;
    const int rowBase = blockIdx.x * 128;

    // stage x -> As[m][k] bf16: lanes cover 32 k4-groups of one row each iter
    #pragma unroll
    for (int l = 0; l < 16; ++l) {
        int flat = l * 256 + tid;       // 4096 = 128 rows x 32 k4
        int r = flat >> 5, k4 = flat & 31;
        int row = rowBase + r;
        float4 v = (row < n_nodes) ? x4[row * 32 + k4] : make_float4(0.f, 0.f, 0.f, 0.f);
        uint2 u;
        u.x = bf16rne(v.x) | (bf16rne(v.y) << 16);
        u.y = bf16rne(v.z) | (bf16rne(v.w) << 16);
        *(uint2*)&Asu[r][k4 * 4] = u;
    }
    // stage W2^T -> Bs[n][k] bf16 (already bf16 in global, coalesced 8B)
    #pragma unroll
    for (int l = 0; l < 16; ++l) {
        int flat = l * 256 + tid;       // 4096 = 128 n x 32 kq
        int n = flat >> 5, kq = flat & 31;
        uint2 w = *(const uint2*)&W2bT[n * 128 + kq * 4];
        *(uint2*)&Bsu[n][kq * 4] = w;
    }

    // fp32 per-node scalar packs from global x (L2-hot after staging)
    {
        int r = tid & 127, h = tid >> 7;
        int row = rowBase + r;
        if (row < n_nodes) {
            const float4* wa4 = (const float4*)(h ? wqA : wkA);
            const float4* wg4 = (const float4*)(h ? wqG : wkG);
            float sA = 0.f, sG = 0.f;
            #pragma unroll 8
            for (int k4 = 0; k4 < 32; ++k4) {
                float4 xv = x4[row * 32 + k4];
                float4 wa = wa4[k4], wg = wg4[k4];
                sA = fmaf(xv.x, wa.x, fmaf(xv.y, wa.y, fmaf(xv.z, wa.z, fmaf(xv.w, wa.w, sA))));
                sG = fmaf(xv.x, wg.x, fmaf(xv.y, wg.y, fmaf(xv.z, wg.z, fmaf(xv.w, wg.w, sG))));
            }
            if (h) dstPack[row] = make_float2(sA, sG);
            else   srcPack[row] = make_float2(sA, sG);
        }
    }
    __syncthreads();

    const int wave = tid >> 6, lane = tid & 63;
    const int ln = lane & 15, quad = lane >> 4;
    const int wm = (wave & 1) * 64, wn = (wave >> 1) * 64;

    f32x4 acc[4][4];
    #pragma unroll
    for (int i = 0; i < 4; ++i)
        #pragma unroll
        for (int j = 0; j < 4; ++j) acc[i][j] = (f32x4){0.f, 0.f, 0.f, 0.f};

    #pragma unroll
    for (int kc = 0; kc < 4; ++kc) {
        int k0 = kc * 32 + quad * 8;
        bf16x8 afr[4], bfr[4];
        #pragma unroll
        for (int mt = 0; mt < 4; ++mt)
            afr[mt] = *(const bf16x8*)&Asu[wm + mt * 16 + ln][k0];
        #pragma unroll
        for (int nt = 0; nt < 4; ++nt)
            bfr[nt] = *(const bf16x8*)&Bsu[wn + nt * 16 + ln][k0];
        #pragma unroll
        for (int mt = 0; mt < 4; ++mt)
            #pragma unroll
            for (int nt = 0; nt < 4; ++nt)
                acc[mt][nt] = __builtin_amdgcn_mfma_f32_16x16x32_bf16(
                    afr[mt], bfr[nt], acc[mt][nt], 0, 0, 0);
    }

    // epilogue: D col = ln, row = quad*4 + reg; pack col pairs via shfl_xor(1)
    #pragma unroll
    for (int nt = 0; nt < 4; ++nt) {
        int col = wn + nt * 16 + ln;
        float cb = c2[col];
        #pragma unroll
        for (int mt = 0; mt < 4; ++mt) {
            #pragma unroll
            for (int r = 0; r < 4; ++r) {
                int row = rowBase + wm + mt * 16 + quad * 4 + r;
                float v = acc[mt][nt][r] + cb;
                float pv = __shfl_xor(v, 1, 64);
                if (!(ln & 1) && row < n_nodes) {
                    Vmb[row * 64 + (col >> 1)] = bf16rne(v) | (bf16rne(pv) << 16);
                }
            }
        }
    }
}

// edge1a: rule-MLP (8 edges/thread) + dst>>8 histogram fused.
__global__ void __launch_bounds__(256) edge1a_kernel(
    const float4* __restrict__ erf, const int* __restrict__ dsts,
    const float4* __restrict__ w1t, const float2* __restrict__ w12,
    const float* __restrict__ rule_b2,
    float* __restrict__ b_out, int* __restrict__ hpart, int n_edges)
{
    __shared__ float4 s_w1t[128];
    __shared__ float2 s_w12[128];
    __shared__ int cnt[256];
    const int tid = threadIdx.x;
    if (tid < 128) { s_w1t[tid] = w1t[tid]; s_w12[tid] = w12[tid]; }
    cnt[tid] = 0;
    __syncthreads();

    const int eb = blockIdx.x * 2048;
    float4 rf[8];
    #pragma unroll
    for (int q = 0; q < 8; ++q) {
        int e = eb + q * 256 + tid;
        rf[q] = erf[min(e, n_edges - 1)];
        if (e < n_edges) atomicAdd(&cnt[dsts[e] >> 8], 1);
    }

    float bacc[8] = {0.f, 0.f, 0.f, 0.f, 0.f, 0.f, 0.f, 0.f};
    #pragma unroll 2
    for (int j = 0; j < 128; ++j) {
        float4 w = s_w1t[j];
        float2 c = s_w12[j];
        #pragma unroll
        for (int q = 0; q < 8; ++q) {
            float h = fmaf(rf[q].x, w.x, fmaf(rf[q].y, w.y,
                      fmaf(rf[q].z, w.z, fmaf(rf[q].w, w.w, c.x))));
            bacc[q] = fmaf(fmaxf(h, 0.f), c.y, bacc[q]);
        }
    }

    const float rb2 = rule_b2[0];
    #pragma unroll
    for (int q = 0; q < 8; ++q) {
        int e = eb + q * 256 + tid;
        if (e < n_edges) b_out[e] = bacc[q] + rb2;
    }
    __syncthreads();
    hpart[blockIdx.x * 256 + tid] = cnt[tid];
}

// hscan2: hred+hscan fused. 1 block x 1024 threads: 4-way row-split column
// sums (coalesced), LDS reduce, 256-bucket exclusive scan.
__global__ void __launch_bounds__(1024) hscan2_kernel(
    const int* __restrict__ hpart, int* __restrict__ bucketCursor,
    int* __restrict__ bucketStart, int* __restrict__ rowPtr,
    int nblk, int n_nodes, int n_edges)
{
    __shared__ int part[4][256];
    __shared__ int sdata[256];
    const int tid = threadIdx.x;
    const int b = tid & 255, g = tid >> 8;
    int s = 0;
    for (int r = g; r < nblk; r += 4) s += hpart[r * 256 + b];
    part[g][b] = s;
    __syncthreads();
    if (tid < 256) sdata[tid] = part[0][tid] + part[1][tid] + part[2][tid] + part[3][tid];
    __syncthreads();
    #pragma unroll
    for (int off = 1; off < 256; off <<= 1) {
        int t = 0;
        if (tid < 256 && tid >= off) t = sdata[tid - off];
        __syncthreads();
        if (tid < 256) sdata[tid] += t;
        __syncthreads();
    }
    if (tid < 256) {
        int tot = part[0][tid] + part[1][tid] + part[2][tid] + part[3][tid];
        int excl = sdata[tid] - tot;
        bucketCursor[tid] = excl;
        bucketStart[tid] = excl;
    }
    if (tid == 0) rowPtr[n_nodes] = n_edges;
}

// sort1 (fused with edge tail): per edge compute gamma/e_val in-register,
// store both coalesced, then LDS-binned coarse scatter into bucket regions
// (bucket = dst >> 8) with coalesced run copy. (R16 form — staging restored.)
__global__ void __launch_bounds__(256) sort1_kernel(
    const int* __restrict__ ei, const int* __restrict__ et,
    const float4* __restrict__ erf, const float* __restrict__ b_out,
    const float* __restrict__ grw,
    const float2* __restrict__ srcPack, const float2* __restrict__ dstPack,
    const float* __restrict__ relA, const float* __restrict__ consts,
    float* __restrict__ e_val, float* __restrict__ gamma_out,
    int* __restrict__ bucketCursor, float2* __restrict__ tmp, int n_edges)
{
    __shared__ float2 data[4096];          // 32 KB
    __shared__ unsigned char slotB[4096];  // 4 KB
    __shared__ int cnt[256], rk[256], base_[256], run[256], scanBuf[256];
    __shared__ float s_relA[16];
    const int tid = threadIdx.x;
    const int blockBase = blockIdx.x * 4096;
    const int total = min(4096, n_edges - blockBase);

    cnt[tid] = 0;
    rk[tid] = 0;
    if (tid < 16) s_relA[tid] = relA[tid];
    __syncthreads();

    const float c0 = consts[0], c1 = consts[1];
    const float g0 = grw[0], g1 = grw[1], g2 = grw[2], g3 = grw[3];

    int   d_[16];
    float ev_[16];
    int   pk_[16];
    #pragma unroll
    for (int i = 0; i < 16; ++i) {
        int e = blockBase + i * 256 + tid;
        if (e < n_edges) {
            int s = ei[e];
            int d = ei[n_edges + e];
            int t = et[e];
            float4 rf = erf[e];
            float b = b_out[e];
            float2 ss = srcPack[s], dd = dstPack[d];
            float pre = ss.x + dd.x + s_relA[t] + c0;
            float e_base = pre >= 0.f ? pre : 0.2f * pre;
            float gl = fmaf(rf.x, g0, fmaf(rf.y, g1,
                       fmaf(rf.z, g2, fmaf(rf.w, g3, c1 + ss.y + dd.y))));
            float gamma = 1.f / (1.f + __expf(-gl));
            float ev = e_base + gamma * b;
            gamma_out[e] = gamma;
            e_val[e] = ev;
            d_[i]  = d;
            ev_[i] = ev;
            pk_[i] = (s & 0xFFFF) | ((t & 15) << 16) | ((d & 255) << 20);
            atomicAdd(&cnt[d >> 8], 1);
        } else {
            d_[i] = -1;
        }
    }
    __syncthreads();

    int c = cnt[tid];
    scanBuf[tid] = c;
    __syncthreads();
    #pragma unroll
    for (int off = 1; off < 256; off <<= 1) {
        int t = (tid >= off) ? scanBuf[tid - off] : 0;
        __syncthreads();
        scanBuf[tid] += t;
        __syncthreads();
    }
    base_[tid] = scanBuf[tid] - c;
    run[tid] = c ? atomicAdd(&bucketCursor[tid], c) : 0;
    __syncthreads();

    #pragma unroll
    for (int i = 0; i < 16; ++i) {
        if (d_[i] >= 0) {
            int b = d_[i] >> 8;
            int r = atomicAdd(&rk[b], 1);
            int slot = base_[b] + r;
            data[slot] = make_float2(ev_[i], __int_as_float(pk_[i]));
            slotB[slot] = (unsigned char)b;
        }
    }
    __syncthreads();

    for (int j = tid; j < total; j += 256) {
        int b = slotB[j];
        tmp[run[b] + (j - base_[b])] = data[j];
    }
}

// sort2: per-bucket exact CSR placement, single-pass: bucket entries cached
// in 24 unrolled registers (tmp read once); guarded global overflow path.
// Grid is nbuck (~196) blocks on 256 CUs -> grid-limited, VGPRs free.
#define S2_MAXB 24
__global__ void __launch_bounds__(256) sort2_kernel(
    const int* __restrict__ bucketStart, const float2* __restrict__ tmp,
    float2* __restrict__ payload, int* __restrict__ rowPtr,
    int n_nodes, int n_edges, int nbuck)
{
    __shared__ int cnt[256], cur[256], sdata[256];
    const int tid = threadIdx.x;
    const int b = blockIdx.x;
    const int d0 = b * 256;
    const int lo = bucketStart[b];
    const int hi = (b == nbuck - 1) ? n_edges : bucketStart[b + 1];

    cnt[tid] = 0;
    __syncthreads();

    float2 v_[S2_MAXB];
    #pragma unroll
    for (int i = 0; i < S2_MAXB; ++i) {
        int j = lo + i * 256 + tid;
        if (j < hi) {
            v_[i] = tmp[j];
            atomicAdd(&cnt[(__float_as_uint(v_[i].y) >> 20) & 255], 1);
        }
    }
    // overflow path (not expected for this input; correctness guard)
    for (int j = lo + S2_MAXB * 256 + tid; j < hi; j += 256)
        atomicAdd(&cnt[(__float_as_uint(tmp[j].y) >> 20) & 255], 1);
    __syncthreads();

    int c = cnt[tid];
    sdata[tid] = c;
    __syncthreads();
    #pragma unroll
    for (int off = 1; off < 256; off <<= 1) {
        int t = (tid >= off) ? sdata[tid - off] : 0;
        __syncthreads();
        sdata[tid] += t;
        __syncthreads();
    }
    int excl = sdata[tid] - c;
    cur[tid] = lo + excl;
    if (d0 + tid < n_nodes) rowPtr[d0 + tid] = lo + excl;
    __syncthreads();

    #pragma unroll
    for (int i = 0; i < S2_MAXB; ++i) {
        int j = lo + i * 256 + tid;
        if (j < hi) {
            unsigned pk = __float_as_uint(v_[i].y);
            int dl = (pk >> 20) & 255;
            int pos = atomicAdd(&cur[dl], 1);
            unsigned st = (pk & 0xFFFFu) | (((pk >> 16) & 15u) << 27);
            payload[pos] = make_float2(v_[i].x, __uint_as_float(st));
        }
    }
    for (int j = lo + S2_MAXB * 256 + tid; j < hi; j += 256) {
        float2 p = tmp[j];
        unsigned pk = __float_as_uint(p.y);
        int dl = (pk >> 20) & 255;
        int pos = atomicAdd(&cur[dl], 1);
        unsigned st = (pk & 0xFFFFu) | (((pk >> 16) & 15u) << 27);
        payload[pos] = make_float2(p.x, __uint_as_float(st));
    }
}

// one wave per dst node. Softmax via shuffles, then (av,st) staged in LDS:
// inner loop does 1 broadcast ds_read_b64 + 1 Vmb load per edge. relM
// contribution applied once per type in the epilogue (linearity).
__global__ void __launch_bounds__(256) gather_kernel(
    const int* __restrict__ rowPtr, const float2* __restrict__ payload,
    const unsigned* __restrict__ Vmb, const float* __restrict__ relM,
    float* __restrict__ out, float2* __restrict__ nodeMS, int n_nodes)
{
    __shared__ float2 s_relM[16 * 64];   // 8 KB: relM as float2[type][lane]
    __shared__ float2 s_pay[4][64];      // 2 KB: per-wave (av, st) staging
    __shared__ float  s_ts[4][16];       // per-wave per-type alpha sums
    const int tid = threadIdx.x;
    const float2* relM2 = (const float2*)relM;
    #pragma unroll
    for (int i = 0; i < 4; ++i) s_relM[i * 256 + tid] = relM2[i * 256 + tid];

    const int lane = tid & 63;
    const int w = tid >> 6;
    if (lane < 16) s_ts[w][lane] = 0.f;
    __syncthreads();

    int d = blockIdx.x * 4 + w;
    if (d >= n_nodes) return;
    int start = rowPtr[d];
    int deg = rowPtr[d + 1] - start;

    float acc0 = 0.f, acc1 = 0.f;
    float m = -INFINITY, inv;

    // consume s_pay[w][0..cnt): batch-8 Vmb gathers
    auto accrun = [&](int cnt) {
        for (int k = 0; k < cnt; k += 8) {
            float a[8];
            int ss[8];
            #pragma unroll
            for (int i = 0; i < 8; ++i) {
                float2 p = s_pay[w][k + i];   // wave-uniform addr: broadcast
                a[i]  = p.x;
                ss[i] = __float_as_int(p.y) & 0x7FFFFFF;
            }
            unsigned v[8];
            #pragma unroll
            for (int i = 0; i < 8; ++i) v[i] = Vmb[ss[i] * 64 + lane];
            #pragma unroll
            for (int i = 0; i < 8; ++i) {
                acc0 = fmaf(a[i], bflo(v[i]), acc0);
                acc1 = fmaf(a[i], bfhi(v[i]), acc1);
            }
        }
    };

    if (deg <= 64) {
        float ev = -INFINITY;
        int st = 0;
        if (lane < deg) {
            float2 p = payload[start + lane];
            ev = p.x;
            st = __float_as_int(p.y);
        }
        m = wave_max(ev);
        float ex = (lane < deg) ? __expf(ev - m) : 0.f;
        float sum = wave_sum(ex);
        inv = 1.f / (sum + 1e-16f);
        float av = ex * inv;
        s_pay[w][lane] = make_float2(av, __int_as_float(st));
        if (lane < deg) atomicAdd(&s_ts[w][((unsigned)st) >> 27], av);
        accrun(deg);
    } else {
        for (int i = lane; i < deg; i += 64) m = fmaxf(m, payload[start + i].x);
        m = wave_max(m);
        float sum = 0.f;
        for (int i = lane; i < deg; i += 64) sum += __expf(payload[start + i].x - m);
        sum = wave_sum(sum);
        inv = 1.f / (sum + 1e-16f);
        for (int c = 0; c < deg; c += 64) {
            int i = c + lane;
            float av = 0.f;
            int st = 0;
            if (i < deg) {
                float2 p = payload[start + i];
                av = __expf(p.x - m) * inv;
                st = __float_as_int(p.y);
            }
            s_pay[w][lane] = make_float2(av, __int_as_float(st));
            if (i < deg) atomicAdd(&s_ts[w][((unsigned)st) >> 27], av);
            accrun(min(64, deg - c));
        }
    }

    // epilogue: per-type relM contribution
    #pragma unroll
    for (int t = 0; t < 16; ++t) {
        float ts = s_ts[w][t];
        float2 rm = s_relM[t * 64 + lane];
        acc0 = fmaf(ts, rm.x, acc0);
        acc1 = fmaf(ts, rm.y, acc1);
    }

    if (lane == 0) nodeMS[d] = make_float2(m, inv);
    *(float2*)&out[d * 128 + lane * 2] = make_float2(acc0, acc1);
}

// fully-coalesced alpha: alpha[e] = exp(e_val[e] - m[d]) * inv[d]
__global__ void __launch_bounds__(256) alpha_kernel(
    const int* __restrict__ ei, const float* __restrict__ e_val,
    const float2* __restrict__ nodeMS, float* __restrict__ alpha_out, int n_edges)
{
    int e = blockIdx.x * blockDim.x + threadIdx.x;
    if (e >= n_edges) return;
    int d = ei[n_edges + e];
    float2 ms = nodeMS[d];
    alpha_out[e] = __expf(e_val[e] - ms.x) * ms.y;
}

extern "C" void kernel_launch(void* const* d_in, const int* in_sizes, int n_in,
                              void* d_out, int out_size, void* d_ws, size_t ws_size,
                              hipStream_t stream)
{
    const float* x        = (const float*)d_in[0];
    const int*   ei       = (const int*)d_in[1];
    const int*   et       = (const int*)d_in[2];
    const float* erf      = (const float*)d_in[3];
    const float* Wq       = (const float*)d_in[5];
    const float* bq       = (const float*)d_in[6];
    const float* Wk       = (const float*)d_in[7];
    const float* bk       = (const float*)d_in[8];
    const float* Wv       = (const float*)d_in[9];
    const float* bv       = (const float*)d_in[10];
    const float* rel_emb  = (const float*)d_in[11];
    const float* attn_vec = (const float*)d_in[12];
    const float* rule_w1  = (const float*)d_in[13];
    const float* rule_b1  = (const float*)d_in[14];
    const float* rule_w2  = (const float*)d_in[15];
    const float* rule_b2  = (const float*)d_in[16];
    const float* grw      = (const float*)d_in[17];
    const float* grb      = (const float*)d_in[18];
    const float* gnw      = (const float*)d_in[19];
    const float* gnb      = (const float*)d_in[20];
    const float* msg_w    = (const float*)d_in[21];
    const float* msg_b    = (const float*)d_in[22];

    const int n_nodes = in_sizes[0] / 128;
    const int n_edges = in_sizes[2];
    const int nab = (n_edges + 2047) / 2048;  // edge1a blocks (hpart rows)
    const int nhb = (n_edges + 4095) / 4096;  // sort1 blocks
    const int nbuck = (n_nodes + 255) / 256;  // coarse buckets (<= 256)

    float* ws = (float*)d_ws;
    size_t off = 0;
    unsigned* Vmb  = (unsigned*)(ws + off); off += (size_t)n_nodes * 64;
    float2* payload = (float2*)(ws + off); off += 2 * (size_t)n_edges;
    float2* tmpPay  = (float2*)(ws + off); off += 2 * (size_t)n_edges;
    float* e_val   = ws + off; off += n_edges;
    float* srcPack = ws + off; off += 2 * (size_t)n_nodes;
    float* dstPack = ws + off; off += 2 * (size_t)n_nodes;
    float2* nodeMS = (float2*)(ws + off); off += 2 * (size_t)n_nodes;
    int*   rowPtr  = (int*)(ws + off); off += n_nodes + 4;
    int*   hpart   = (int*)(ws + off); off += (size_t)nab * 256;
    int*   bucketCursor = (int*)(ws + off); off += 256;
    int*   bucketStart  = (int*)(ws + off); off += 256;
    unsigned short* W2bT = (unsigned short*)(ws + off); off += 128 * 64;
    float* c2      = ws + off; off += 128;
    float* wkA     = ws + off; off += 128;
    float* wqA     = ws + off; off += 128;
    float* wkG     = ws + off; off += 128;
    float* wqG     = ws + off; off += 128;
    float* relA    = ws + off; off += 16;
    float* relM    = ws + off; off += 16 * 128;
    float* consts  = ws + off; off += 2;
    off += 2;  // 16B alignment for w1t
    float4* w1t    = (float4*)(ws + off); off += 128 * 4;
    float2* w12    = (float2*)(ws + off); off += 128 * 2;

    float* out       = (float*)d_out;
    float* alpha_out = out + (size_t)n_nodes * 128;
    float* gamma_out = alpha_out + n_edges;
    float* b_out     = gamma_out + n_edges;

    hipLaunchKernelGGL(precompute_kernel, dim3(146), dim3(128), 0, stream,
                       Wq, bq, Wk, bk, Wv, bv, rel_emb, attn_vec, msg_w, msg_b,
                       gnw, grb, gnb, rule_w1, rule_b1, rule_w2,
                       W2bT, c2, wkA, wqA, wkG, wqG, relA, relM, consts, w1t, w12);

    hipLaunchKernelGGL(node_kernel, dim3((n_nodes + 127) / 128), dim3(256), 0, stream,
                       (const float4*)x, W2bT, c2,
                       wkA, wqA, wkG, wqG, Vmb, (float2*)srcPack, (float2*)dstPack,
                       n_nodes);

    hipLaunchKernelGGL(edge1a_kernel, dim3(nab), dim3(256), 0, stream,
                       (const float4*)erf, ei + n_edges,
                       (const float4*)w1t, (const float2*)w12,
                       rule_b2, b_out, hpart, n_edges);

    hipLaunchKernelGGL(hscan2_kernel, dim3(1), dim3(1024), 0, stream,
                       hpart, bucketCursor, bucketStart, rowPtr,
                       nab, n_nodes, n_edges);

    hipLaunchKernelGGL(sort1_kernel, dim3(nhb), dim3(256), 0, stream,
                       ei, et, (const float4*)erf, b_out, grw,
                       (const float2*)srcPack, (const float2*)dstPack,
                       relA, consts, e_val, gamma_out,
                       bucketCursor, tmpPay, n_edges);

    hipLaunchKernelGGL(sort2_kernel, dim3(nbuck), dim3(256), 0, stream,
                       bucketStart, tmpPay, payload, rowPtr,
                       n_nodes, n_edges, nbuck);

    hipLaunchKernelGGL(gather_kernel, dim3((n_nodes + 3) / 4), dim3(256), 0, stream,
                       rowPtr, payload, Vmb, relM, out, nodeMS, n_nodes);

    hipLaunchKernelGGL(alpha_kernel, dim3((n_edges + 255) / 256), dim3(256), 0, stream,
                       ei, e_val, nodeMS, alpha_out, n_edges);
}

// Round 12
// 280.506 us; speedup vs baseline: 1.0087x; 1.0087x over previous
//
#include <hip/hip_runtime.h>
#include <math.h>

// ---------------------------------------------------------------------------
// RGAPConv, CSR-gather formulation (R19 = R18 with sort2 reverted to the
// R16 two-pass form — R18 post-mortem: sort1 was innocent; sort2's 24x
// float2 register cache held live across barriers (likely scratch spill)
// is the prime suspect for the R17/R18 +12us regression):
//   sort1:     edge tail fused + LDS-staged coarse scatter (R16 form).
//   sort2:     two-pass per-bucket exact CSR placement (R16 form).
//   hscan2:    hred+hscan merged: 1 block x 1024 threads (kept).
//   gather:    R16 lean loop (LDS (av,st) staging + relM linearity hoist).
//   edge1a:    rule-MLP (8 edges/thread) + dst>>8 histogram fused.
//   node:      MFMA bf16 GEMM (16x16x32), 128x128 tile.
//   alpha:     coalesced per-edge kernel from per-node {m, inv}.
// ---------------------------------------------------------------------------

using bf16x8 = __attribute__((ext_vector_type(8))) short;
using f32x4  = __attribute__((ext_vector_type(4))) float;

__device__ __forceinline__ float wave_max(float v) {
    #pragma unroll
    for (int o = 32; o > 0; o >>= 1) v = fmaxf(v, __shfl_xor(v, o, 64));
    return v;
}
__device__ __forceinline__ float wave_sum(float v) {
    #pragma unroll
    for (int o = 32; o > 0; o >>= 1) v += __shfl_xor(v, o, 64);
    return v;
}

__device__ __forceinline__ unsigned bf16rne(float f) {
    unsigned u = __float_as_uint(f);
    return (u + 0x7FFFu + ((u >> 16) & 1u)) >> 16;  // round-to-nearest-even
}
__device__ __forceinline__ float bflo(unsigned u) { return __uint_as_float(u << 16); }
__device__ __forceinline__ float bfhi(unsigned u) { return __uint_as_float(u & 0xFFFF0000u); }

// grid = 146 blocks x 128 threads. Builds all small tables.
// W2bT is stored TRANSPOSED: W2bT[n*128 + k] = (Wv@msg_w)[k][n] in bf16.
__global__ void __launch_bounds__(128) precompute_kernel(
    const float* __restrict__ Wq, const float* __restrict__ bq,
    const float* __restrict__ Wk, const float* __restrict__ bk,
    const float* __restrict__ Wv, const float* __restrict__ bv,
    const float* __restrict__ rel_emb, const float* __restrict__ attn_vec,
    const float* __restrict__ msg_w, const float* __restrict__ msg_b,
    const float* __restrict__ gnw, const float* __restrict__ grb,
    const float* __restrict__ gnb,
    const float* __restrict__ rule_w1, const float* __restrict__ rule_b1,
    const float* __restrict__ rule_w2,
    unsigned short* __restrict__ W2bT, float* __restrict__ c2,
    float* __restrict__ wkA, float* __restrict__ wqA,
    float* __restrict__ wkG, float* __restrict__ wqG,
    float* __restrict__ relA, float* __restrict__ relM,
    float* __restrict__ consts,
    float4* __restrict__ w1t, float2* __restrict__ w12)
{
    __shared__ float red[128];
    int bid = blockIdx.x, j = threadIdx.x;

    auto blk_reduce = [&](float v) -> float {
        red[j] = v;
        __syncthreads();
        for (int s = 64; s > 0; s >>= 1) {
            if (j < s) red[j] += red[j + s];
            __syncthreads();
        }
        float r = red[0];
        __syncthreads();
        return r;
    };

    if (bid < 128) {
        int i = bid;  // k index
        float acc = 0.f;
        #pragma unroll 8
        for (int k = 0; k < 128; ++k) acc = fmaf(Wv[i * 128 + k], msg_w[k * 128 + j], acc);
        W2bT[j * 128 + i] = (unsigned short)bf16rne(acc);  // transposed store
        float r;
        r = blk_reduce(Wk[i * 128 + j] * attn_vec[j]);        if (j == 0) wkA[i] = r;
        r = blk_reduce(Wq[i * 128 + j] * attn_vec[128 + j]);  if (j == 0) wqA[i] = r;
        r = blk_reduce(Wk[i * 128 + j] * gnw[j]);             if (j == 0) wkG[i] = r;
        r = blk_reduce(Wq[i * 128 + j] * gnw[128 + j]);       if (j == 0) wqG[i] = r;
    } else if (bid < 144) {
        int t = bid - 128;
        float acc = 0.f;
        #pragma unroll 8
        for (int k = 0; k < 128; ++k) acc = fmaf(rel_emb[t * 128 + k], msg_w[k * 128 + j], acc);
        relM[t * 128 + j] = acc;
        float r = blk_reduce(rel_emb[t * 128 + j] * attn_vec[256 + j]);
        if (j == 0) relA[t] = r;
    } else if (bid == 144) {
        float acc = msg_b[j];
        #pragma unroll 8
        for (int k = 0; k < 128; ++k) acc = fmaf(bv[k], msg_w[k * 128 + j], acc);
        c2[j] = acc;
        w1t[j] = make_float4(rule_w1[j], rule_w1[128 + j], rule_w1[256 + j], rule_w1[384 + j]);
        w12[j] = make_float2(rule_b1[j], rule_w2[j]);
    } else {
        float r = blk_reduce(bk[j] * attn_vec[j] + bq[j] * attn_vec[128 + j]);
        if (j == 0) consts[0] = r;
        r = blk_reduce(bk[j] * gnw[j] + bq[j] * gnw[128 + j]);
        if (j == 0) consts[1] = r + grb[0] + gnb[0];
    }
}

// MFMA node GEMM: 128x128 tile/block, 4 waves each own a 64x64 quadrant.
__global__ void __launch_bounds__(256) node_kernel(
    const float4* __restrict__ x4, const unsigned short* __restrict__ W2bT,
    const float* __restrict__ c2,
    const float* __restrict__ wkA, const float* __restrict__ wqA,
    const float* __restrict__ wkG, const float* __restrict__ wqG,
    unsigned* __restrict__ Vmb, float2* __restrict__ srcPack,
    float2* __restrict__ dstPack, int n_nodes)
{
    __shared__ unsigned short Asu[128][136];
    __shared__ unsigned short Bsu[128][136];
    const int tid = threadIdx.x;
    const int rowBase = blockIdx.x * 128;

    // stage x -> As[m][k] bf16: lanes cover 32 k4-groups of one row each iter
    #pragma unroll
    for (int l = 0; l < 16; ++l) {
        int flat = l * 256 + tid;       // 4096 = 128 rows x 32 k4
        int r = flat >> 5, k4 = flat & 31;
        int row = rowBase + r;
        float4 v = (row < n_nodes) ? x4[row * 32 + k4] : make_float4(0.f, 0.f, 0.f, 0.f);
        uint2 u;
        u.x = bf16rne(v.x) | (bf16rne(v.y) << 16);
        u.y = bf16rne(v.z) | (bf16rne(v.w) << 16);
        *(uint2*)&Asu[r][k4 * 4] = u;
    }
    // stage W2^T -> Bs[n][k] bf16 (already bf16 in global, coalesced 8B)
    #pragma unroll
    for (int l = 0; l < 16; ++l) {
        int flat = l * 256 + tid;       // 4096 = 128 n x 32 kq
        int n = flat >> 5, kq = flat & 31;
        uint2 w = *(const uint2*)&W2bT[n * 128 + kq * 4];
        *(uint2*)&Bsu[n][kq * 4] = w;
    }

    // fp32 per-node scalar packs from global x (L2-hot after staging)
    {
        int r = tid & 127, h = tid >> 7;
        int row = rowBase + r;
        if (row < n_nodes) {
            const float4* wa4 = (const float4*)(h ? wqA : wkA);
            const float4* wg4 = (const float4*)(h ? wqG : wkG);
            float sA = 0.f, sG = 0.f;
            #pragma unroll 8
            for (int k4 = 0; k4 < 32; ++k4) {
                float4 xv = x4[row * 32 + k4];
                float4 wa = wa4[k4], wg = wg4[k4];
                sA = fmaf(xv.x, wa.x, fmaf(xv.y, wa.y, fmaf(xv.z, wa.z, fmaf(xv.w, wa.w, sA))));
                sG = fmaf(xv.x, wg.x, fmaf(xv.y, wg.y, fmaf(xv.z, wg.z, fmaf(xv.w, wg.w, sG))));
            }
            if (h) dstPack[row] = make_float2(sA, sG);
            else   srcPack[row] = make_float2(sA, sG);
        }
    }
    __syncthreads();

    const int wave = tid >> 6, lane = tid & 63;
    const int ln = lane & 15, quad = lane >> 4;
    const int wm = (wave & 1) * 64, wn = (wave >> 1) * 64;

    f32x4 acc[4][4];
    #pragma unroll
    for (int i = 0; i < 4; ++i)
        #pragma unroll
        for (int j = 0; j < 4; ++j) acc[i][j] = (f32x4){0.f, 0.f, 0.f, 0.f};

    #pragma unroll
    for (int kc = 0; kc < 4; ++kc) {
        int k0 = kc * 32 + quad * 8;
        bf16x8 afr[4], bfr[4];
        #pragma unroll
        for (int mt = 0; mt < 4; ++mt)
            afr[mt] = *(const bf16x8*)&Asu[wm + mt * 16 + ln][k0];
        #pragma unroll
        for (int nt = 0; nt < 4; ++nt)
            bfr[nt] = *(const bf16x8*)&Bsu[wn + nt * 16 + ln][k0];
        #pragma unroll
        for (int mt = 0; mt < 4; ++mt)
            #pragma unroll
            for (int nt = 0; nt < 4; ++nt)
                acc[mt][nt] = __builtin_amdgcn_mfma_f32_16x16x32_bf16(
                    afr[mt], bfr[nt], acc[mt][nt], 0, 0, 0);
    }

    // epilogue: D col = ln, row = quad*4 + reg; pack col pairs via shfl_xor(1)
    #pragma unroll
    for (int nt = 0; nt < 4; ++nt) {
        int col = wn + nt * 16 + ln;
        float cb = c2[col];
        #pragma unroll
        for (int mt = 0; mt < 4; ++mt) {
            #pragma unroll
            for (int r = 0; r < 4; ++r) {
                int row = rowBase + wm + mt * 16 + quad * 4 + r;
                float v = acc[mt][nt][r] + cb;
                float pv = __shfl_xor(v, 1, 64);
                if (!(ln & 1) && row < n_nodes) {
                    Vmb[row * 64 + (col >> 1)] = bf16rne(v) | (bf16rne(pv) << 16);
                }
            }
        }
    }
}

// edge1a: rule-MLP (8 edges/thread) + dst>>8 histogram fused.
__global__ void __launch_bounds__(256) edge1a_kernel(
    const float4* __restrict__ erf, const int* __restrict__ dsts,
    const float4* __restrict__ w1t, const float2* __restrict__ w12,
    const float* __restrict__ rule_b2,
    float* __restrict__ b_out, int* __restrict__ hpart, int n_edges)
{
    __shared__ float4 s_w1t[128];
    __shared__ float2 s_w12[128];
    __shared__ int cnt[256];
    const int tid = threadIdx.x;
    if (tid < 128) { s_w1t[tid] = w1t[tid]; s_w12[tid] = w12[tid]; }
    cnt[tid] = 0;
    __syncthreads();

    const int eb = blockIdx.x * 2048;
    float4 rf[8];
    #pragma unroll
    for (int q = 0; q < 8; ++q) {
        int e = eb + q * 256 + tid;
        rf[q] = erf[min(e, n_edges - 1)];
        if (e < n_edges) atomicAdd(&cnt[dsts[e] >> 8], 1);
    }

    float bacc[8] = {0.f, 0.f, 0.f, 0.f, 0.f, 0.f, 0.f, 0.f};
    #pragma unroll 2
    for (int j = 0; j < 128; ++j) {
        float4 w = s_w1t[j];
        float2 c = s_w12[j];
        #pragma unroll
        for (int q = 0; q < 8; ++q) {
            float h = fmaf(rf[q].x, w.x, fmaf(rf[q].y, w.y,
                      fmaf(rf[q].z, w.z, fmaf(rf[q].w, w.w, c.x))));
            bacc[q] = fmaf(fmaxf(h, 0.f), c.y, bacc[q]);
        }
    }

    const float rb2 = rule_b2[0];
    #pragma unroll
    for (int q = 0; q < 8; ++q) {
        int e = eb + q * 256 + tid;
        if (e < n_edges) b_out[e] = bacc[q] + rb2;
    }
    __syncthreads();
    hpart[blockIdx.x * 256 + tid] = cnt[tid];
}

// hscan2: hred+hscan fused. 1 block x 1024 threads: 4-way row-split column
// sums (coalesced), LDS reduce, 256-bucket exclusive scan.
__global__ void __launch_bounds__(1024) hscan2_kernel(
    const int* __restrict__ hpart, int* __restrict__ bucketCursor,
    int* __restrict__ bucketStart, int* __restrict__ rowPtr,
    int nblk, int n_nodes, int n_edges)
{
    __shared__ int part[4][256];
    __shared__ int sdata[256];
    const int tid = threadIdx.x;
    const int b = tid & 255, g = tid >> 8;
    int s = 0;
    for (int r = g; r < nblk; r += 4) s += hpart[r * 256 + b];
    part[g][b] = s;
    __syncthreads();
    if (tid < 256) sdata[tid] = part[0][tid] + part[1][tid] + part[2][tid] + part[3][tid];
    __syncthreads();
    #pragma unroll
    for (int off = 1; off < 256; off <<= 1) {
        int t = 0;
        if (tid < 256 && tid >= off) t = sdata[tid - off];
        __syncthreads();
        if (tid < 256) sdata[tid] += t;
        __syncthreads();
    }
    if (tid < 256) {
        int tot = part[0][tid] + part[1][tid] + part[2][tid] + part[3][tid];
        int excl = sdata[tid] - tot;
        bucketCursor[tid] = excl;
        bucketStart[tid] = excl;
    }
    if (tid == 0) rowPtr[n_nodes] = n_edges;
}

// sort1 (fused with edge tail): per edge compute gamma/e_val in-register,
// store both coalesced, then LDS-binned coarse scatter into bucket regions
// (bucket = dst >> 8) with coalesced run copy. (R16 form.)
__global__ void __launch_bounds__(256) sort1_kernel(
    const int* __restrict__ ei, const int* __restrict__ et,
    const float4* __restrict__ erf, const float* __restrict__ b_out,
    const float* __restrict__ grw,
    const float2* __restrict__ srcPack, const float2* __restrict__ dstPack,
    const float* __restrict__ relA, const float* __restrict__ consts,
    float* __restrict__ e_val, float* __restrict__ gamma_out,
    int* __restrict__ bucketCursor, float2* __restrict__ tmp, int n_edges)
{
    __shared__ float2 data[4096];          // 32 KB
    __shared__ unsigned char slotB[4096];  // 4 KB
    __shared__ int cnt[256], rk[256], base_[256], run[256], scanBuf[256];
    __shared__ float s_relA[16];
    const int tid = threadIdx.x;
    const int blockBase = blockIdx.x * 4096;
    const int total = min(4096, n_edges - blockBase);

    cnt[tid] = 0;
    rk[tid] = 0;
    if (tid < 16) s_relA[tid] = relA[tid];
    __syncthreads();

    const float c0 = consts[0], c1 = consts[1];
    const float g0 = grw[0], g1 = grw[1], g2 = grw[2], g3 = grw[3];

    int   d_[16];
    float ev_[16];
    int   pk_[16];
    #pragma unroll
    for (int i = 0; i < 16; ++i) {
        int e = blockBase + i * 256 + tid;
        if (e < n_edges) {
            int s = ei[e];
            int d = ei[n_edges + e];
            int t = et[e];
            float4 rf = erf[e];
            float b = b_out[e];
            float2 ss = srcPack[s], dd = dstPack[d];
            float pre = ss.x + dd.x + s_relA[t] + c0;
            float e_base = pre >= 0.f ? pre : 0.2f * pre;
            float gl = fmaf(rf.x, g0, fmaf(rf.y, g1,
                       fmaf(rf.z, g2, fmaf(rf.w, g3, c1 + ss.y + dd.y))));
            float gamma = 1.f / (1.f + __expf(-gl));
            float ev = e_base + gamma * b;
            gamma_out[e] = gamma;
            e_val[e] = ev;
            d_[i]  = d;
            ev_[i] = ev;
            pk_[i] = (s & 0xFFFF) | ((t & 15) << 16) | ((d & 255) << 20);
            atomicAdd(&cnt[d >> 8], 1);
        } else {
            d_[i] = -1;
        }
    }
    __syncthreads();

    int c = cnt[tid];
    scanBuf[tid] = c;
    __syncthreads();
    #pragma unroll
    for (int off = 1; off < 256; off <<= 1) {
        int t = (tid >= off) ? scanBuf[tid - off] : 0;
        __syncthreads();
        scanBuf[tid] += t;
        __syncthreads();
    }
    base_[tid] = scanBuf[tid] - c;
    run[tid] = c ? atomicAdd(&bucketCursor[tid], c) : 0;
    __syncthreads();

    #pragma unroll
    for (int i = 0; i < 16; ++i) {
        if (d_[i] >= 0) {
            int b = d_[i] >> 8;
            int r = atomicAdd(&rk[b], 1);
            int slot = base_[b] + r;
            data[slot] = make_float2(ev_[i], __int_as_float(pk_[i]));
            slotB[slot] = (unsigned char)b;
        }
    }
    __syncthreads();

    for (int j = tid; j < total; j += 256) {
        int b = slotB[j];
        tmp[run[b] + (j - base_[b])] = data[j];
    }
}

// sort2: per-bucket exact CSR placement, two-pass (R16 form): histogram
// pass over tmp, local scan (writes rowPtr), placement pass re-reads tmp.
__global__ void __launch_bounds__(256) sort2_kernel(
    const int* __restrict__ bucketStart, const float2* __restrict__ tmp,
    float2* __restrict__ payload, int* __restrict__ rowPtr,
    int n_nodes, int n_edges, int nbuck)
{
    __shared__ int cnt[256], cur[256], sdata[256];
    const int tid = threadIdx.x;
    const int b = blockIdx.x;
    const int d0 = b * 256;
    const int lo = bucketStart[b];
    const int hi = (b == nbuck - 1) ? n_edges : bucketStart[b + 1];

    cnt[tid] = 0;
    __syncthreads();
    for (int j = lo + tid; j < hi; j += 256) {
        unsigned pk = __float_as_uint(tmp[j].y);
        atomicAdd(&cnt[(pk >> 20) & 255], 1);
    }
    __syncthreads();

    int c = cnt[tid];
    sdata[tid] = c;
    __syncthreads();
    #pragma unroll
    for (int off = 1; off < 256; off <<= 1) {
        int t = (tid >= off) ? sdata[tid - off] : 0;
        __syncthreads();
        sdata[tid] += t;
        __syncthreads();
    }
    int excl = sdata[tid] - c;
    cur[tid] = lo + excl;
    if (d0 + tid < n_nodes) rowPtr[d0 + tid] = lo + excl;
    __syncthreads();

    for (int j = lo + tid; j < hi; j += 256) {
        float2 p = tmp[j];
        unsigned pk = __float_as_uint(p.y);
        int dl = (pk >> 20) & 255;
        int pos = atomicAdd(&cur[dl], 1);
        unsigned st = (pk & 0xFFFFu) | (((pk >> 16) & 15u) << 27);
        payload[pos] = make_float2(p.x, __uint_as_float(st));
    }
}

// one wave per dst node. Softmax via shuffles, then (av,st) staged in LDS:
// inner loop does 1 broadcast ds_read_b64 + 1 Vmb load per edge. relM
// contribution applied once per type in the epilogue (linearity).
__global__ void __launch_bounds__(256) gather_kernel(
    const int* __restrict__ rowPtr, const float2* __restrict__ payload,
    const unsigned* __restrict__ Vmb, const float* __restrict__ relM,
    float* __restrict__ out, float2* __restrict__ nodeMS, int n_nodes)
{
    __shared__ float2 s_relM[16 * 64];   // 8 KB: relM as float2[type][lane]
    __shared__ float2 s_pay[4][64];      // 2 KB: per-wave (av, st) staging
    __shared__ float  s_ts[4][16];       // per-wave per-type alpha sums
    const int tid = threadIdx.x;
    const float2* relM2 = (const float2*)relM;
    #pragma unroll
    for (int i = 0; i < 4; ++i) s_relM[i * 256 + tid] = relM2[i * 256 + tid];

    const int lane = tid & 63;
    const int w = tid >> 6;
    if (lane < 16) s_ts[w][lane] = 0.f;
    __syncthreads();

    int d = blockIdx.x * 4 + w;
    if (d >= n_nodes) return;
    int start = rowPtr[d];
    int deg = rowPtr[d + 1] - start;

    float acc0 = 0.f, acc1 = 0.f;
    float m = -INFINITY, inv;

    // consume s_pay[w][0..cnt): batch-8 Vmb gathers
    auto accrun = [&](int cnt) {
        for (int k = 0; k < cnt; k += 8) {
            float a[8];
            int ss[8];
            #pragma unroll
            for (int i = 0; i < 8; ++i) {
                float2 p = s_pay[w][k + i];   // wave-uniform addr: broadcast
                a[i]  = p.x;
                ss[i] = __float_as_int(p.y) & 0x7FFFFFF;
            }
            unsigned v[8];
            #pragma unroll
            for (int i = 0; i < 8; ++i) v[i] = Vmb[ss[i] * 64 + lane];
            #pragma unroll
            for (int i = 0; i < 8; ++i) {
                acc0 = fmaf(a[i], bflo(v[i]), acc0);
                acc1 = fmaf(a[i], bfhi(v[i]), acc1);
            }
        }
    };

    if (deg <= 64) {
        float ev = -INFINITY;
        int st = 0;
        if (lane < deg) {
            float2 p = payload[start + lane];
            ev = p.x;
            st = __float_as_int(p.y);
        }
        m = wave_max(ev);
        float ex = (lane < deg) ? __expf(ev - m) : 0.f;
        float sum = wave_sum(ex);
        inv = 1.f / (sum + 1e-16f);
        float av = ex * inv;
        s_pay[w][lane] = make_float2(av, __int_as_float(st));
        if (lane < deg) atomicAdd(&s_ts[w][((unsigned)st) >> 27], av);
        accrun(deg);
    } else {
        for (int i = lane; i < deg; i += 64) m = fmaxf(m, payload[start + i].x);
        m = wave_max(m);
        float sum = 0.f;
        for (int i = lane; i < deg; i += 64) sum += __expf(payload[start + i].x - m);
        sum = wave_sum(sum);
        inv = 1.f / (sum + 1e-16f);
        for (int c = 0; c < deg; c += 64) {
            int i = c + lane;
            float av = 0.f;
            int st = 0;
            if (i < deg) {
                float2 p = payload[start + i];
                av = __expf(p.x - m) * inv;
                st = __float_as_int(p.y);
            }
            s_pay[w][lane] = make_float2(av, __int_as_float(st));
            if (i < deg) atomicAdd(&s_ts[w][((unsigned)st) >> 27], av);
            accrun(min(64, deg - c));
        }
    }

    // epilogue: per-type relM contribution
    #pragma unroll
    for (int t = 0; t < 16; ++t) {
        float ts = s_ts[w][t];
        float2 rm = s_relM[t * 64 + lane];
        acc0 = fmaf(ts, rm.x, acc0);
        acc1 = fmaf(ts, rm.y, acc1);
    }

    if (lane == 0) nodeMS[d] = make_float2(m, inv);
    *(float2*)&out[d * 128 + lane * 2] = make_float2(acc0, acc1);
}

// fully-coalesced alpha: alpha[e] = exp(e_val[e] - m[d]) * inv[d]
__global__ void __launch_bounds__(256) alpha_kernel(
    const int* __restrict__ ei, const float* __restrict__ e_val,
    const float2* __restrict__ nodeMS, float* __restrict__ alpha_out, int n_edges)
{
    int e = blockIdx.x * blockDim.x + threadIdx.x;
    if (e >= n_edges) return;
    int d = ei[n_edges + e];
    float2 ms = nodeMS[d];
    alpha_out[e] = __expf(e_val[e] - ms.x) * ms.y;
}

extern "C" void kernel_launch(void* const* d_in, const int* in_sizes, int n_in,
                              void* d_out, int out_size, void* d_ws, size_t ws_size,
                              hipStream_t stream)
{
    const float* x        = (const float*)d_in[0];
    const int*   ei       = (const int*)d_in[1];
    const int*   et       = (const int*)d_in[2];
    const float* erf      = (const float*)d_in[3];
    const float* Wq       = (const float*)d_in[5];
    const float* bq       = (const float*)d_in[6];
    const float* Wk       = (const float*)d_in[7];
    const float* bk       = (const float*)d_in[8];
    const float* Wv       = (const float*)d_in[9];
    const float* bv       = (const float*)d_in[10];
    const float* rel_emb  = (const float*)d_in[11];
    const float* attn_vec = (const float*)d_in[12];
    const float* rule_w1  = (const float*)d_in[13];
    const float* rule_b1  = (const float*)d_in[14];
    const float* rule_w2  = (const float*)d_in[15];
    const float* rule_b2  = (const float*)d_in[16];
    const float* grw      = (const float*)d_in[17];
    const float* grb      = (const float*)d_in[18];
    const float* gnw      = (const float*)d_in[19];
    const float* gnb      = (const float*)d_in[20];
    const float* msg_w    = (const float*)d_in[21];
    const float* msg_b    = (const float*)d_in[22];

    const int n_nodes = in_sizes[0] / 128;
    const int n_edges = in_sizes[2];
    const int nab = (n_edges + 2047) / 2048;  // edge1a blocks (hpart rows)
    const int nhb = (n_edges + 4095) / 4096;  // sort1 blocks
    const int nbuck = (n_nodes + 255) / 256;  // coarse buckets (<= 256)

    float* ws = (float*)d_ws;
    size_t off = 0;
    unsigned* Vmb  = (unsigned*)(ws + off); off += (size_t)n_nodes * 64;
    float2* payload = (float2*)(ws + off); off += 2 * (size_t)n_edges;
    float2* tmpPay  = (float2*)(ws + off); off += 2 * (size_t)n_edges;
    float* e_val   = ws + off; off += n_edges;
    float* srcPack = ws + off; off += 2 * (size_t)n_nodes;
    float* dstPack = ws + off; off += 2 * (size_t)n_nodes;
    float2* nodeMS = (float2*)(ws + off); off += 2 * (size_t)n_nodes;
    int*   rowPtr  = (int*)(ws + off); off += n_nodes + 4;
    int*   hpart   = (int*)(ws + off); off += (size_t)nab * 256;
    int*   bucketCursor = (int*)(ws + off); off += 256;
    int*   bucketStart  = (int*)(ws + off); off += 256;
    unsigned short* W2bT = (unsigned short*)(ws + off); off += 128 * 64;
    float* c2      = ws + off; off += 128;
    float* wkA     = ws + off; off += 128;
    float* wqA     = ws + off; off += 128;
    float* wkG     = ws + off; off += 128;
    float* wqG     = ws + off; off += 128;
    float* relA    = ws + off; off += 16;
    float* relM    = ws + off; off += 16 * 128;
    float* consts  = ws + off; off += 2;
    off += 2;  // 16B alignment for w1t
    float4* w1t    = (float4*)(ws + off); off += 128 * 4;
    float2* w12    = (float2*)(ws + off); off += 128 * 2;

    float* out       = (float*)d_out;
    float* alpha_out = out + (size_t)n_nodes * 128;
    float* gamma_out = alpha_out + n_edges;
    float* b_out     = gamma_out + n_edges;

    hipLaunchKernelGGL(precompute_kernel, dim3(146), dim3(128), 0, stream,
                       Wq, bq, Wk, bk, Wv, bv, rel_emb, attn_vec, msg_w, msg_b,
                       gnw, grb, gnb, rule_w1, rule_b1, rule_w2,
                       W2bT, c2, wkA, wqA, wkG, wqG, relA, relM, consts, w1t, w12);

    hipLaunchKernelGGL(node_kernel, dim3((n_nodes + 127) / 128), dim3(256), 0, stream,
                       (const float4*)x, W2bT, c2,
                       wkA, wqA, wkG, wqG, Vmb, (float2*)srcPack, (float2*)dstPack,
                       n_nodes);

    hipLaunchKernelGGL(edge1a_kernel, dim3(nab), dim3(256), 0, stream,
                       (const float4*)erf, ei + n_edges,
                       (const float4*)w1t, (const float2*)w12,
                       rule_b2, b_out, hpart, n_edges);

    hipLaunchKernelGGL(hscan2_kernel, dim3(1), dim3(1024), 0, stream,
                       hpart, bucketCursor, bucketStart, rowPtr,
                       nab, n_nodes, n_edges);

    hipLaunchKernelGGL(sort1_kernel, dim3(nhb), dim3(256), 0, stream,
                       ei, et, (const float4*)erf, b_out, grw,
                       (const float2*)srcPack, (const float2*)dstPack,
                       relA, consts, e_val, gamma_out,
                       bucketCursor, tmpPay, n_edges);

    hipLaunchKernelGGL(sort2_kernel, dim3(nbuck), dim3(256), 0, stream,
                       bucketStart, tmpPay, payload, rowPtr,
                       n_nodes, n_edges, nbuck);

    hipLaunchKernelGGL(gather_kernel, dim3((n_nodes + 3) / 4), dim3(256), 0, stream,
                       rowPtr, payload, Vmb, relM, out, nodeMS, n_nodes);

    hipLaunchKernelGGL(alpha_kernel, dim3((n_edges + 255) / 256), dim3(256), 0, stream,
                       ei, e_val, nodeMS, alpha_out, n_edges);
}

// Round 13
// 268.755 us; speedup vs baseline: 1.0528x; 1.0437x over previous
//
#include <hip/hip_runtime.h>
#include <math.h>

// ---------------------------------------------------------------------------
// RGAPConv, CSR-gather formulation (R20 = R16 config + 8-wave node kernel):
//   hred/hscan: parallel bucket reduce (256 blocks) + 256-total scan —
//              RESTORED (R17-R19 post-mortem: single-block hscan2 read
//              400KB on one CU, ~+9us; sort1/sort2 exonerated by ablation).
//   node:      512 threads / 8 waves per 128x128 tile — R19 profile showed
//              43us @ 15% occupancy, 1.5 blocks/CU grid-starved; 8 waves
//              halve staging iters and split MFMA 8 ways (32x64/wave).
//   sort1:     edge tail fused + LDS-staged coarse scatter (R16 form).
//   sort2:     two-pass per-bucket exact CSR placement (R16 form).
//   gather:    R16 lean loop (LDS (av,st) staging + relM linearity hoist).
//   edge1a:    rule-MLP (8 edges/thread) + dst>>8 histogram fused.
//   alpha:     coalesced per-edge kernel from per-node {m, inv}.
// ---------------------------------------------------------------------------

using bf16x8 = __attribute__((ext_vector_type(8))) short;
using f32x4  = __attribute__((ext_vector_type(4))) float;

__device__ __forceinline__ float wave_max(float v) {
    #pragma unroll
    for (int o = 32; o > 0; o >>= 1) v = fmaxf(v, __shfl_xor(v, o, 64));
    return v;
}
__device__ __forceinline__ float wave_sum(float v) {
    #pragma unroll
    for (int o = 32; o > 0; o >>= 1) v += __shfl_xor(v, o, 64);
    return v;
}

__device__ __forceinline__ unsigned bf16rne(float f) {
    unsigned u = __float_as_uint(f);
    return (u + 0x7FFFu + ((u >> 16) & 1u)) >> 16;  // round-to-nearest-even
}
__device__ __forceinline__ float bflo(unsigned u) { return __uint_as_float(u << 16); }
__device__ __forceinline__ float bfhi(unsigned u) { return __uint_as_float(u & 0xFFFF0000u); }

// grid = 146 blocks x 128 threads. Builds all small tables.
// W2bT is stored TRANSPOSED: W2bT[n*128 + k] = (Wv@msg_w)[k][n] in bf16.
__global__ void __launch_bounds__(128) precompute_kernel(
    const float* __restrict__ Wq, const float* __restrict__ bq,
    const float* __restrict__ Wk, const float* __restrict__ bk,
    const float* __restrict__ Wv, const float* __restrict__ bv,
    const float* __restrict__ rel_emb, const float* __restrict__ attn_vec,
    const float* __restrict__ msg_w, const float* __restrict__ msg_b,
    const float* __restrict__ gnw, const float* __restrict__ grb,
    const float* __restrict__ gnb,
    const float* __restrict__ rule_w1, const float* __restrict__ rule_b1,
    const float* __restrict__ rule_w2,
    unsigned short* __restrict__ W2bT, float* __restrict__ c2,
    float* __restrict__ wkA, float* __restrict__ wqA,
    float* __restrict__ wkG, float* __restrict__ wqG,
    float* __restrict__ relA, float* __restrict__ relM,
    float* __restrict__ consts,
    float4* __restrict__ w1t, float2* __restrict__ w12)
{
    __shared__ float red[128];
    int bid = blockIdx.x, j = threadIdx.x;

    auto blk_reduce = [&](float v) -> float {
        red[j] = v;
        __syncthreads();
        for (int s = 64; s > 0; s >>= 1) {
            if (j < s) red[j] += red[j + s];
            __syncthreads();
        }
        float r = red[0];
        __syncthreads();
        return r;
    };

    if (bid < 128) {
        int i = bid;  // k index
        float acc = 0.f;
        #pragma unroll 8
        for (int k = 0; k < 128; ++k) acc = fmaf(Wv[i * 128 + k], msg_w[k * 128 + j], acc);
        W2bT[j * 128 + i] = (unsigned short)bf16rne(acc);  // transposed store
        float r;
        r = blk_reduce(Wk[i * 128 + j] * attn_vec[j]);        if (j == 0) wkA[i] = r;
        r = blk_reduce(Wq[i * 128 + j] * attn_vec[128 + j]);  if (j == 0) wqA[i] = r;
        r = blk_reduce(Wk[i * 128 + j] * gnw[j]);             if (j == 0) wkG[i] = r;
        r = blk_reduce(Wq[i * 128 + j] * gnw[128 + j]);       if (j == 0) wqG[i] = r;
    } else if (bid < 144) {
        int t = bid - 128;
        float acc = 0.f;
        #pragma unroll 8
        for (int k = 0; k < 128; ++k) acc = fmaf(rel_emb[t * 128 + k], msg_w[k * 128 + j], acc);
        relM[t * 128 + j] = acc;
        float r = blk_reduce(rel_emb[t * 128 + j] * attn_vec[256 + j]);
        if (j == 0) relA[t] = r;
    } else if (bid == 144) {
        float acc = msg_b[j];
        #pragma unroll 8
        for (int k = 0; k < 128; ++k) acc = fmaf(bv[k], msg_w[k * 128 + j], acc);
        c2[j] = acc;
        w1t[j] = make_float4(rule_w1[j], rule_w1[128 + j], rule_w1[256 + j], rule_w1[384 + j]);
        w12[j] = make_float2(rule_b1[j], rule_w2[j]);
    } else {
        float r = blk_reduce(bk[j] * attn_vec[j] + bq[j] * attn_vec[128 + j]);
        if (j == 0) consts[0] = r;
        r = blk_reduce(bk[j] * gnw[j] + bq[j] * gnw[128 + j]);
        if (j == 0) consts[1] = r + grb[0] + gnb[0];
    }
}

// MFMA node GEMM: 128x128 tile/block, 512 threads / 8 waves; each wave owns
// a 32x64 quadrant (wm = (wave&3)*32, wn = (wave>>2)*64). Staging in 8 iters.
// Pack split: k-halves across tid>>8, combined via LDS after the barrier.
__global__ void __launch_bounds__(512) node_kernel(
    const float4* __restrict__ x4, const unsigned short* __restrict__ W2bT,
    const float* __restrict__ c2,
    const float* __restrict__ wkA, const float* __restrict__ wqA,
    const float* __restrict__ wkG, const float* __restrict__ wqG,
    unsigned* __restrict__ Vmb, float2* __restrict__ srcPack,
    float2* __restrict__ dstPack, int n_nodes)
{
    __shared__ unsigned short Asu[128][136];
    __shared__ unsigned short Bsu[128][136];
    __shared__ float2 sPk[2][256];
    const int tid = threadIdx.x;
    const int rowBase = blockIdx.x * 128;

    // stage x -> As[m][k] bf16: 4096 k4-units over 512 threads = 8 iters
    #pragma unroll
    for (int l = 0; l < 8; ++l) {
        int flat = l * 512 + tid;       // 4096 = 128 rows x 32 k4
        int r = flat >> 5, k4 = flat & 31;
        int row = rowBase + r;
        float4 v = (row < n_nodes) ? x4[row * 32 + k4] : make_float4(0.f, 0.f, 0.f, 0.f);
        uint2 u;
        u.x = bf16rne(v.x) | (bf16rne(v.y) << 16);
        u.y = bf16rne(v.z) | (bf16rne(v.w) << 16);
        *(uint2*)&Asu[r][k4 * 4] = u;
    }
    // stage W2^T -> Bs[n][k] bf16 (already bf16 in global, coalesced 8B)
    #pragma unroll
    for (int l = 0; l < 8; ++l) {
        int flat = l * 512 + tid;       // 4096 = 128 n x 32 kq
        int n = flat >> 5, kq = flat & 31;
        uint2 w = *(const uint2*)&W2bT[n * 128 + kq * 4];
        *(uint2*)&Bsu[n][kq * 4] = w;
    }

    // fp32 per-node scalar packs: 256 (r,h)-units x 2 k-halves
    {
        int unit = tid & 255, half = tid >> 8;
        int r = unit & 127, h = unit >> 7;
        int row = rowBase + r;
        float sA = 0.f, sG = 0.f;
        if (row < n_nodes) {
            const float4* wa4 = (const float4*)(h ? wqA : wkA);
            const float4* wg4 = (const float4*)(h ? wqG : wkG);
            int kb = half * 16;
            #pragma unroll 8
            for (int k4 = 0; k4 < 16; ++k4) {
                float4 xv = x4[row * 32 + kb + k4];
                float4 wa = wa4[kb + k4], wg = wg4[kb + k4];
                sA = fmaf(xv.x, wa.x, fmaf(xv.y, wa.y, fmaf(xv.z, wa.z, fmaf(xv.w, wa.w, sA))));
                sG = fmaf(xv.x, wg.x, fmaf(xv.y, wg.y, fmaf(xv.z, wg.z, fmaf(xv.w, wg.w, sG))));
            }
        }
        sPk[half][unit] = make_float2(sA, sG);
    }
    __syncthreads();

    // combine pack halves and store (waves 0-3; waves 4-7 proceed to MFMA)
    if (tid < 256) {
        int r = tid & 127, h = tid >> 7;
        int row = rowBase + r;
        if (row < n_nodes) {
            float2 a = sPk[0][tid], b = sPk[1][tid];
            float2 res = make_float2(a.x + b.x, a.y + b.y);
            if (h) dstPack[row] = res;
            else   srcPack[row] = res;
        }
    }

    const int wave = tid >> 6, lane = tid & 63;
    const int ln = lane & 15, quad = lane >> 4;
    const int wm = (wave & 3) * 32, wn = (wave >> 2) * 64;

    f32x4 acc[2][4];
    #pragma unroll
    for (int i = 0; i < 2; ++i)
        #pragma unroll
        for (int j = 0; j < 4; ++j) acc[i][j] = (f32x4){0.f, 0.f, 0.f, 0.f};

    #pragma unroll
    for (int kc = 0; kc < 4; ++kc) {
        int k0 = kc * 32 + quad * 8;
        bf16x8 afr[2], bfr[4];
        #pragma unroll
        for (int mt = 0; mt < 2; ++mt)
            afr[mt] = *(const bf16x8*)&Asu[wm + mt * 16 + ln][k0];
        #pragma unroll
        for (int nt = 0; nt < 4; ++nt)
            bfr[nt] = *(const bf16x8*)&Bsu[wn + nt * 16 + ln][k0];
        #pragma unroll
        for (int mt = 0; mt < 2; ++mt)
            #pragma unroll
            for (int nt = 0; nt < 4; ++nt)
                acc[mt][nt] = __builtin_amdgcn_mfma_f32_16x16x32_bf16(
                    afr[mt], bfr[nt], acc[mt][nt], 0, 0, 0);
    }

    // epilogue: D col = ln, row = quad*4 + reg; pack col pairs via shfl_xor(1)
    #pragma unroll
    for (int nt = 0; nt < 4; ++nt) {
        int col = wn + nt * 16 + ln;
        float cb = c2[col];
        #pragma unroll
        for (int mt = 0; mt < 2; ++mt) {
            #pragma unroll
            for (int r = 0; r < 4; ++r) {
                int row = rowBase + wm + mt * 16 + quad * 4 + r;
                float v = acc[mt][nt][r] + cb;
                float pv = __shfl_xor(v, 1, 64);
                if (!(ln & 1) && row < n_nodes) {
                    Vmb[row * 64 + (col >> 1)] = bf16rne(v) | (bf16rne(pv) << 16);
                }
            }
        }
    }
}

// edge1a: rule-MLP (8 edges/thread) + dst>>8 histogram fused.
__global__ void __launch_bounds__(256) edge1a_kernel(
    const float4* __restrict__ erf, const int* __restrict__ dsts,
    const float4* __restrict__ w1t, const float2* __restrict__ w12,
    const float* __restrict__ rule_b2,
    float* __restrict__ b_out, int* __restrict__ hpart, int n_edges)
{
    __shared__ float4 s_w1t[128];
    __shared__ float2 s_w12[128];
    __shared__ int cnt[256];
    const int tid = threadIdx.x;
    if (tid < 128) { s_w1t[tid] = w1t[tid]; s_w12[tid] = w12[tid]; }
    cnt[tid] = 0;
    __syncthreads();

    const int eb = blockIdx.x * 2048;
    float4 rf[8];
    #pragma unroll
    for (int q = 0; q < 8; ++q) {
        int e = eb + q * 256 + tid;
        rf[q] = erf[min(e, n_edges - 1)];
        if (e < n_edges) atomicAdd(&cnt[dsts[e] >> 8], 1);
    }

    float bacc[8] = {0.f, 0.f, 0.f, 0.f, 0.f, 0.f, 0.f, 0.f};
    #pragma unroll 2
    for (int j = 0; j < 128; ++j) {
        float4 w = s_w1t[j];
        float2 c = s_w12[j];
        #pragma unroll
        for (int q = 0; q < 8; ++q) {
            float h = fmaf(rf[q].x, w.x, fmaf(rf[q].y, w.y,
                      fmaf(rf[q].z, w.z, fmaf(rf[q].w, w.w, c.x))));
            bacc[q] = fmaf(fmaxf(h, 0.f), c.y, bacc[q]);
        }
    }

    const float rb2 = rule_b2[0];
    #pragma unroll
    for (int q = 0; q < 8; ++q) {
        int e = eb + q * 256 + tid;
        if (e < n_edges) b_out[e] = bacc[q] + rb2;
    }
    __syncthreads();
    hpart[blockIdx.x * 256 + tid] = cnt[tid];
}

// hred: 256 blocks; block b reduces hpart column b (nblk entries) in parallel.
__global__ void __launch_bounds__(256) hred_kernel(
    const int* __restrict__ hpart, int* __restrict__ bucketTotal, int nblk)
{
    __shared__ int sdata[256];
    const int tid = threadIdx.x;
    const int b = blockIdx.x;
    int s = 0;
    for (int i = tid; i < nblk; i += 256) s += hpart[i * 256 + b];
    sdata[tid] = s;
    __syncthreads();
    #pragma unroll
    for (int off2 = 128; off2 > 0; off2 >>= 1) {
        if (tid < off2) sdata[tid] += sdata[tid + off2];
        __syncthreads();
    }
    if (tid == 0) bucketTotal[b] = sdata[0];
}

// hscan: single block scans the 256 bucket totals -> bucketCursor (mutable,
// for sort1) + bucketStart (read-only, for sort2) + rowPtr[n_nodes].
__global__ void __launch_bounds__(256) hscan_kernel(
    const int* __restrict__ bucketTotal, int* __restrict__ bucketCursor,
    int* __restrict__ bucketStart, int* __restrict__ rowPtr,
    int n_nodes, int n_edges)
{
    __shared__ int sdata[256];
    const int tid = threadIdx.x;
    int s = bucketTotal[tid];
    sdata[tid] = s;
    __syncthreads();
    #pragma unroll
    for (int off = 1; off < 256; off <<= 1) {
        int t = (tid >= off) ? sdata[tid - off] : 0;
        __syncthreads();
        sdata[tid] += t;
        __syncthreads();
    }
    int excl = sdata[tid] - s;
    bucketCursor[tid] = excl;
    bucketStart[tid] = excl;
    if (tid == 0) rowPtr[n_nodes] = n_edges;
}

// sort1 (fused with edge tail): per edge compute gamma/e_val in-register,
// store both coalesced, then LDS-binned coarse scatter into bucket regions
// (bucket = dst >> 8) with coalesced run copy. (R16 form.)
__global__ void __launch_bounds__(256) sort1_kernel(
    const int* __restrict__ ei, const int* __restrict__ et,
    const float4* __restrict__ erf, const float* __restrict__ b_out,
    const float* __restrict__ grw,
    const float2* __restrict__ srcPack, const float2* __restrict__ dstPack,
    const float* __restrict__ relA, const float* __restrict__ consts,
    float* __restrict__ e_val, float* __restrict__ gamma_out,
    int* __restrict__ bucketCursor, float2* __restrict__ tmp, int n_edges)
{
    __shared__ float2 data[4096];          // 32 KB
    __shared__ unsigned char slotB[4096];  // 4 KB
    __shared__ int cnt[256], rk[256], base_[256], run[256], scanBuf[256];
    __shared__ float s_relA[16];
    const int tid = threadIdx.x;
    const int blockBase = blockIdx.x * 4096;
    const int total = min(4096, n_edges - blockBase);

    cnt[tid] = 0;
    rk[tid] = 0;
    if (tid < 16) s_relA[tid] = relA[tid];
    __syncthreads();

    const float c0 = consts[0], c1 = consts[1];
    const float g0 = grw[0], g1 = grw[1], g2 = grw[2], g3 = grw[3];

    int   d_[16];
    float ev_[16];
    int   pk_[16];
    #pragma unroll
    for (int i = 0; i < 16; ++i) {
        int e = blockBase + i * 256 + tid;
        if (e < n_edges) {
            int s = ei[e];
            int d = ei[n_edges + e];
            int t = et[e];
            float4 rf = erf[e];
            float b = b_out[e];
            float2 ss = srcPack[s], dd = dstPack[d];
            float pre = ss.x + dd.x + s_relA[t] + c0;
            float e_base = pre >= 0.f ? pre : 0.2f * pre;
            float gl = fmaf(rf.x, g0, fmaf(rf.y, g1,
                       fmaf(rf.z, g2, fmaf(rf.w, g3, c1 + ss.y + dd.y))));
            float gamma = 1.f / (1.f + __expf(-gl));
            float ev = e_base + gamma * b;
            gamma_out[e] = gamma;
            e_val[e] = ev;
            d_[i]  = d;
            ev_[i] = ev;
            pk_[i] = (s & 0xFFFF) | ((t & 15) << 16) | ((d & 255) << 20);
            atomicAdd(&cnt[d >> 8], 1);
        } else {
            d_[i] = -1;
        }
    }
    __syncthreads();

    int c = cnt[tid];
    scanBuf[tid] = c;
    __syncthreads();
    #pragma unroll
    for (int off = 1; off < 256; off <<= 1) {
        int t = (tid >= off) ? scanBuf[tid - off] : 0;
        __syncthreads();
        scanBuf[tid] += t;
        __syncthreads();
    }
    base_[tid] = scanBuf[tid] - c;
    run[tid] = c ? atomicAdd(&bucketCursor[tid], c) : 0;
    __syncthreads();

    #pragma unroll
    for (int i = 0; i < 16; ++i) {
        if (d_[i] >= 0) {
            int b = d_[i] >> 8;
            int r = atomicAdd(&rk[b], 1);
            int slot = base_[b] + r;
            data[slot] = make_float2(ev_[i], __int_as_float(pk_[i]));
            slotB[slot] = (unsigned char)b;
        }
    }
    __syncthreads();

    for (int j = tid; j < total; j += 256) {
        int b = slotB[j];
        tmp[run[b] + (j - base_[b])] = data[j];
    }
}

// sort2: per-bucket exact CSR placement, two-pass (R16 form): histogram
// pass over tmp, local scan (writes rowPtr), placement pass re-reads tmp.
__global__ void __launch_bounds__(256) sort2_kernel(
    const int* __restrict__ bucketStart, const float2* __restrict__ tmp,
    float2* __restrict__ payload, int* __restrict__ rowPtr,
    int n_nodes, int n_edges, int nbuck)
{
    __shared__ int cnt[256], cur[256], sdata[256];
    const int tid = threadIdx.x;
    const int b = blockIdx.x;
    const int d0 = b * 256;
    const int lo = bucketStart[b];
    const int hi = (b == nbuck - 1) ? n_edges : bucketStart[b + 1];

    cnt[tid] = 0;
    __syncthreads();
    for (int j = lo + tid; j < hi; j += 256) {
        unsigned pk = __float_as_uint(tmp[j].y);
        atomicAdd(&cnt[(pk >> 20) & 255], 1);
    }
    __syncthreads();

    int c = cnt[tid];
    sdata[tid] = c;
    __syncthreads();
    #pragma unroll
    for (int off = 1; off < 256; off <<= 1) {
        int t = (tid >= off) ? sdata[tid - off] : 0;
        __syncthreads();
        sdata[tid] += t;
        __syncthreads();
    }
    int excl = sdata[tid] - c;
    cur[tid] = lo + excl;
    if (d0 + tid < n_nodes) rowPtr[d0 + tid] = lo + excl;
    __syncthreads();

    for (int j = lo + tid; j < hi; j += 256) {
        float2 p = tmp[j];
        unsigned pk = __float_as_uint(p.y);
        int dl = (pk >> 20) & 255;
        int pos = atomicAdd(&cur[dl], 1);
        unsigned st = (pk & 0xFFFFu) | (((pk >> 16) & 15u) << 27);
        payload[pos] = make_float2(p.x, __uint_as_float(st));
    }
}

// one wave per dst node. Softmax via shuffles, then (av,st) staged in LDS:
// inner loop does 1 broadcast ds_read_b64 + 1 Vmb load per edge. relM
// contribution applied once per type in the epilogue (linearity).
__global__ void __launch_bounds__(256) gather_kernel(
    const int* __restrict__ rowPtr, const float2* __restrict__ payload,
    const unsigned* __restrict__ Vmb, const float* __restrict__ relM,
    float* __restrict__ out, float2* __restrict__ nodeMS, int n_nodes)
{
    __shared__ float2 s_relM[16 * 64];   // 8 KB: relM as float2[type][lane]
    __shared__ float2 s_pay[4][64];      // 2 KB: per-wave (av, st) staging
    __shared__ float  s_ts[4][16];       // per-wave per-type alpha sums
    const int tid = threadIdx.x;
    const float2* relM2 = (const float2*)relM;
    #pragma unroll
    for (int i = 0; i < 4; ++i) s_relM[i * 256 + tid] = relM2[i * 256 + tid];

    const int lane = tid & 63;
    const int w = tid >> 6;
    if (lane < 16) s_ts[w][lane] = 0.f;
    __syncthreads();

    int d = blockIdx.x * 4 + w;
    if (d >= n_nodes) return;
    int start = rowPtr[d];
    int deg = rowPtr[d + 1] - start;

    float acc0 = 0.f, acc1 = 0.f;
    float m = -INFINITY, inv;

    // consume s_pay[w][0..cnt): batch-8 Vmb gathers
    auto accrun = [&](int cnt) {
        for (int k = 0; k < cnt; k += 8) {
            float a[8];
            int ss[8];
            #pragma unroll
            for (int i = 0; i < 8; ++i) {
                float2 p = s_pay[w][k + i];   // wave-uniform addr: broadcast
                a[i]  = p.x;
                ss[i] = __float_as_int(p.y) & 0x7FFFFFF;
            }
            unsigned v[8];
            #pragma unroll
            for (int i = 0; i < 8; ++i) v[i] = Vmb[ss[i] * 64 + lane];
            #pragma unroll
            for (int i = 0; i < 8; ++i) {
                acc0 = fmaf(a[i], bflo(v[i]), acc0);
                acc1 = fmaf(a[i], bfhi(v[i]), acc1);
            }
        }
    };

    if (deg <= 64) {
        float ev = -INFINITY;
        int st = 0;
        if (lane < deg) {
            float2 p = payload[start + lane];
            ev = p.x;
            st = __float_as_int(p.y);
        }
        m = wave_max(ev);
        float ex = (lane < deg) ? __expf(ev - m) : 0.f;
        float sum = wave_sum(ex);
        inv = 1.f / (sum + 1e-16f);
        float av = ex * inv;
        s_pay[w][lane] = make_float2(av, __int_as_float(st));
        if (lane < deg) atomicAdd(&s_ts[w][((unsigned)st) >> 27], av);
        accrun(deg);
    } else {
        for (int i = lane; i < deg; i += 64) m = fmaxf(m, payload[start + i].x);
        m = wave_max(m);
        float sum = 0.f;
        for (int i = lane; i < deg; i += 64) sum += __expf(payload[start + i].x - m);
        sum = wave_sum(sum);
        inv = 1.f / (sum + 1e-16f);
        for (int c = 0; c < deg; c += 64) {
            int i = c + lane;
            float av = 0.f;
            int st = 0;
            if (i < deg) {
                float2 p = payload[start + i];
                av = __expf(p.x - m) * inv;
                st = __float_as_int(p.y);
            }
            s_pay[w][lane] = make_float2(av, __int_as_float(st));
            if (i < deg) atomicAdd(&s_ts[w][((unsigned)st) >> 27], av);
            accrun(min(64, deg - c));
        }
    }

    // epilogue: per-type relM contribution
    #pragma unroll
    for (int t = 0; t < 16; ++t) {
        float ts = s_ts[w][t];
        float2 rm = s_relM[t * 64 + lane];
        acc0 = fmaf(ts, rm.x, acc0);
        acc1 = fmaf(ts, rm.y, acc1);
    }

    if (lane == 0) nodeMS[d] = make_float2(m, inv);
    *(float2*)&out[d * 128 + lane * 2] = make_float2(acc0, acc1);
}

// fully-coalesced alpha: alpha[e] = exp(e_val[e] - m[d]) * inv[d]
__global__ void __launch_bounds__(256) alpha_kernel(
    const int* __restrict__ ei, const float* __restrict__ e_val,
    const float2* __restrict__ nodeMS, float* __restrict__ alpha_out, int n_edges)
{
    int e = blockIdx.x * blockDim.x + threadIdx.x;
    if (e >= n_edges) return;
    int d = ei[n_edges + e];
    float2 ms = nodeMS[d];
    alpha_out[e] = __expf(e_val[e] - ms.x) * ms.y;
}

extern "C" void kernel_launch(void* const* d_in, const int* in_sizes, int n_in,
                              void* d_out, int out_size, void* d_ws, size_t ws_size,
                              hipStream_t stream)
{
    const float* x        = (const float*)d_in[0];
    const int*   ei       = (const int*)d_in[1];
    const int*   et       = (const int*)d_in[2];
    const float* erf      = (const float*)d_in[3];
    const float* Wq       = (const float*)d_in[5];
    const float* bq       = (const float*)d_in[6];
    const float* Wk       = (const float*)d_in[7];
    const float* bk       = (const float*)d_in[8];
    const float* Wv       = (const float*)d_in[9];
    const float* bv       = (const float*)d_in[10];
    const float* rel_emb  = (const float*)d_in[11];
    const float* attn_vec = (const float*)d_in[12];
    const float* rule_w1  = (const float*)d_in[13];
    const float* rule_b1  = (const float*)d_in[14];
    const float* rule_w2  = (const float*)d_in[15];
    const float* rule_b2  = (const float*)d_in[16];
    const float* grw      = (const float*)d_in[17];
    const float* grb      = (const float*)d_in[18];
    const float* gnw      = (const float*)d_in[19];
    const float* gnb      = (const float*)d_in[20];
    const float* msg_w    = (const float*)d_in[21];
    const float* msg_b    = (const float*)d_in[22];

    const int n_nodes = in_sizes[0] / 128;
    const int n_edges = in_sizes[2];
    const int nab = (n_edges + 2047) / 2048;  // edge1a blocks (hpart rows)
    const int nhb = (n_edges + 4095) / 4096;  // sort1 blocks
    const int nbuck = (n_nodes + 255) / 256;  // coarse buckets (<= 256)

    float* ws = (float*)d_ws;
    size_t off = 0;
    unsigned* Vmb  = (unsigned*)(ws + off); off += (size_t)n_nodes * 64;
    float2* payload = (float2*)(ws + off); off += 2 * (size_t)n_edges;
    float2* tmpPay  = (float2*)(ws + off); off += 2 * (size_t)n_edges;
    float* e_val   = ws + off; off += n_edges;
    float* srcPack = ws + off; off += 2 * (size_t)n_nodes;
    float* dstPack = ws + off; off += 2 * (size_t)n_nodes;
    float2* nodeMS = (float2*)(ws + off); off += 2 * (size_t)n_nodes;
    int*   rowPtr  = (int*)(ws + off); off += n_nodes + 4;
    int*   hpart   = (int*)(ws + off); off += (size_t)nab * 256;
    int*   bucketCursor = (int*)(ws + off); off += 256;
    int*   bucketStart  = (int*)(ws + off); off += 256;
    int*   bucketTotal  = (int*)(ws + off); off += 256;
    unsigned short* W2bT = (unsigned short*)(ws + off); off += 128 * 64;
    float* c2      = ws + off; off += 128;
    float* wkA     = ws + off; off += 128;
    float* wqA     = ws + off; off += 128;
    float* wkG     = ws + off; off += 128;
    float* wqG     = ws + off; off += 128;
    float* relA    = ws + off; off += 16;
    float* relM    = ws + off; off += 16 * 128;
    float* consts  = ws + off; off += 2;
    off += 2;  // 16B alignment for w1t
    float4* w1t    = (float4*)(ws + off); off += 128 * 4;
    float2* w12    = (float2*)(ws + off); off += 128 * 2;

    float* out       = (float*)d_out;
    float* alpha_out = out + (size_t)n_nodes * 128;
    float* gamma_out = alpha_out + n_edges;
    float* b_out     = gamma_out + n_edges;

    hipLaunchKernelGGL(precompute_kernel, dim3(146), dim3(128), 0, stream,
                       Wq, bq, Wk, bk, Wv, bv, rel_emb, attn_vec, msg_w, msg_b,
                       gnw, grb, gnb, rule_w1, rule_b1, rule_w2,
                       W2bT, c2, wkA, wqA, wkG, wqG, relA, relM, consts, w1t, w12);

    hipLaunchKernelGGL(node_kernel, dim3((n_nodes + 127) / 128), dim3(512), 0, stream,
                       (const float4*)x, W2bT, c2,
                       wkA, wqA, wkG, wqG, Vmb, (float2*)srcPack, (float2*)dstPack,
                       n_nodes);

    hipLaunchKernelGGL(edge1a_kernel, dim3(nab), dim3(256), 0, stream,
                       (const float4*)erf, ei + n_edges,
                       (const float4*)w1t, (const float2*)w12,
                       rule_b2, b_out, hpart, n_edges);

    hipLaunchKernelGGL(hred_kernel, dim3(256), dim3(256), 0, stream,
                       hpart, bucketTotal, nab);

    hipLaunchKernelGGL(hscan_kernel, dim3(1), dim3(256), 0, stream,
                       bucketTotal, bucketCursor, bucketStart, rowPtr,
                       n_nodes, n_edges);

    hipLaunchKernelGGL(sort1_kernel, dim3(nhb), dim3(256), 0, stream,
                       ei, et, (const float4*)erf, b_out, grw,
                       (const float2*)srcPack, (const float2*)dstPack,
                       relA, consts, e_val, gamma_out,
                       bucketCursor, tmpPay, n_edges);

    hipLaunchKernelGGL(sort2_kernel, dim3(nbuck), dim3(256), 0, stream,
                       bucketStart, tmpPay, payload, rowPtr,
                       n_nodes, n_edges, nbuck);

    hipLaunchKernelGGL(gather_kernel, dim3((n_nodes + 3) / 4), dim3(256), 0, stream,
                       rowPtr, payload, Vmb, relM, out, nodeMS, n_nodes);

    hipLaunchKernelGGL(alpha_kernel, dim3((n_edges + 255) / 256), dim3(256), 0, stream,
                       ei, e_val, nodeMS, alpha_out, n_edges);
}

// Round 14
// 267.471 us; speedup vs baseline: 1.0579x; 1.0048x over previous
//
#include <hip/hip_runtime.h>
#include <math.h>

// ---------------------------------------------------------------------------
// RGAPConv, CSR-gather formulation (R21 = R20 + pair-processed gather):
//   gather:    pair-processing — lane halves own even/odd edges; uint2 Vmb
//              reads (4 dims/lane), halving VMEM+LDS instructions per edge;
//              type-split relM epilogue + shfl_xor(32) combine; float4 out.
//   node:      512 threads / 8 waves per 128x128 tile (R20).
//   hred/hscan: parallel bucket reduce + 256-total scan (R20).
//   sort1:     edge tail fused + LDS-staged coarse scatter (R16 form).
//   sort2:     two-pass per-bucket exact CSR placement (R16 form).
//   edge1a:    rule-MLP (8 edges/thread) + dst>>8 histogram fused.
//   alpha:     coalesced per-edge kernel from per-node {m, inv}.
// ---------------------------------------------------------------------------

using bf16x8 = __attribute__((ext_vector_type(8))) short;
using f32x4  = __attribute__((ext_vector_type(4))) float;

__device__ __forceinline__ float wave_max(float v) {
    #pragma unroll
    for (int o = 32; o > 0; o >>= 1) v = fmaxf(v, __shfl_xor(v, o, 64));
    return v;
}
__device__ __forceinline__ float wave_sum(float v) {
    #pragma unroll
    for (int o = 32; o > 0; o >>= 1) v += __shfl_xor(v, o, 64);
    return v;
}

__device__ __forceinline__ unsigned bf16rne(float f) {
    unsigned u = __float_as_uint(f);
    return (u + 0x7FFFu + ((u >> 16) & 1u)) >> 16;  // round-to-nearest-even
}
__device__ __forceinline__ float bflo(unsigned u) { return __uint_as_float(u << 16); }
__device__ __forceinline__ float bfhi(unsigned u) { return __uint_as_float(u & 0xFFFF0000u); }

// grid = 146 blocks x 128 threads. Builds all small tables.
// W2bT is stored TRANSPOSED: W2bT[n*128 + k] = (Wv@msg_w)[k][n] in bf16.
__global__ void __launch_bounds__(128) precompute_kernel(
    const float* __restrict__ Wq, const float* __restrict__ bq,
    const float* __restrict__ Wk, const float* __restrict__ bk,
    const float* __restrict__ Wv, const float* __restrict__ bv,
    const float* __restrict__ rel_emb, const float* __restrict__ attn_vec,
    const float* __restrict__ msg_w, const float* __restrict__ msg_b,
    const float* __restrict__ gnw, const float* __restrict__ grb,
    const float* __restrict__ gnb,
    const float* __restrict__ rule_w1, const float* __restrict__ rule_b1,
    const float* __restrict__ rule_w2,
    unsigned short* __restrict__ W2bT, float* __restrict__ c2,
    float* __restrict__ wkA, float* __restrict__ wqA,
    float* __restrict__ wkG, float* __restrict__ wqG,
    float* __restrict__ relA, float* __restrict__ relM,
    float* __restrict__ consts,
    float4* __restrict__ w1t, float2* __restrict__ w12)
{
    __shared__ float red[128];
    int bid = blockIdx.x, j = threadIdx.x;

    auto blk_reduce = [&](float v) -> float {
        red[j] = v;
        __syncthreads();
        for (int s = 64; s > 0; s >>= 1) {
            if (j < s) red[j] += red[j + s];
            __syncthreads();
        }
        float r = red[0];
        __syncthreads();
        return r;
    };

    if (bid < 128) {
        int i = bid;  // k index
        float acc = 0.f;
        #pragma unroll 8
        for (int k = 0; k < 128; ++k) acc = fmaf(Wv[i * 128 + k], msg_w[k * 128 + j], acc);
        W2bT[j * 128 + i] = (unsigned short)bf16rne(acc);  // transposed store
        float r;
        r = blk_reduce(Wk[i * 128 + j] * attn_vec[j]);        if (j == 0) wkA[i] = r;
        r = blk_reduce(Wq[i * 128 + j] * attn_vec[128 + j]);  if (j == 0) wqA[i] = r;
        r = blk_reduce(Wk[i * 128 + j] * gnw[j]);             if (j == 0) wkG[i] = r;
        r = blk_reduce(Wq[i * 128 + j] * gnw[128 + j]);       if (j == 0) wqG[i] = r;
    } else if (bid < 144) {
        int t = bid - 128;
        float acc = 0.f;
        #pragma unroll 8
        for (int k = 0; k < 128; ++k) acc = fmaf(rel_emb[t * 128 + k], msg_w[k * 128 + j], acc);
        relM[t * 128 + j] = acc;
        float r = blk_reduce(rel_emb[t * 128 + j] * attn_vec[256 + j]);
        if (j == 0) relA[t] = r;
    } else if (bid == 144) {
        float acc = msg_b[j];
        #pragma unroll 8
        for (int k = 0; k < 128; ++k) acc = fmaf(bv[k], msg_w[k * 128 + j], acc);
        c2[j] = acc;
        w1t[j] = make_float4(rule_w1[j], rule_w1[128 + j], rule_w1[256 + j], rule_w1[384 + j]);
        w12[j] = make_float2(rule_b1[j], rule_w2[j]);
    } else {
        float r = blk_reduce(bk[j] * attn_vec[j] + bq[j] * attn_vec[128 + j]);
        if (j == 0) consts[0] = r;
        r = blk_reduce(bk[j] * gnw[j] + bq[j] * gnw[128 + j]);
        if (j == 0) consts[1] = r + grb[0] + gnb[0];
    }
}

// MFMA node GEMM: 128x128 tile/block, 512 threads / 8 waves; each wave owns
// a 32x64 quadrant (wm = (wave&3)*32, wn = (wave>>2)*64). Staging in 8 iters.
__global__ void __launch_bounds__(512) node_kernel(
    const float4* __restrict__ x4, const unsigned short* __restrict__ W2bT,
    const float* __restrict__ c2,
    const float* __restrict__ wkA, const float* __restrict__ wqA,
    const float* __restrict__ wkG, const float* __restrict__ wqG,
    unsigned* __restrict__ Vmb, float2* __restrict__ srcPack,
    float2* __restrict__ dstPack, int n_nodes)
{
    __shared__ unsigned short Asu[128][136];
    __shared__ unsigned short Bsu[128][136];
    __shared__ float2 sPk[2][256];
    const int tid = threadIdx.x;
    const int rowBase = blockIdx.x * 128;

    // stage x -> As[m][k] bf16: 4096 k4-units over 512 threads = 8 iters
    #pragma unroll
    for (int l = 0; l < 8; ++l) {
        int flat = l * 512 + tid;       // 4096 = 128 rows x 32 k4
        int r = flat >> 5, k4 = flat & 31;
        int row = rowBase + r;
        float4 v = (row < n_nodes) ? x4[row * 32 + k4] : make_float4(0.f, 0.f, 0.f, 0.f);
        uint2 u;
        u.x = bf16rne(v.x) | (bf16rne(v.y) << 16);
        u.y = bf16rne(v.z) | (bf16rne(v.w) << 16);
        *(uint2*)&Asu[r][k4 * 4] = u;
    }
    // stage W2^T -> Bs[n][k] bf16 (already bf16 in global, coalesced 8B)
    #pragma unroll
    for (int l = 0; l < 8; ++l) {
        int flat = l * 512 + tid;       // 4096 = 128 n x 32 kq
        int n = flat >> 5, kq = flat & 31;
        uint2 w = *(const uint2*)&W2bT[n * 128 + kq * 4];
        *(uint2*)&Bsu[n][kq * 4] = w;
    }

    // fp32 per-node scalar packs: 256 (r,h)-units x 2 k-halves
    {
        int unit = tid & 255, half = tid >> 8;
        int r = unit & 127, h = unit >> 7;
        int row = rowBase + r;
        float sA = 0.f, sG = 0.f;
        if (row < n_nodes) {
            const float4* wa4 = (const float4*)(h ? wqA : wkA);
            const float4* wg4 = (const float4*)(h ? wqG : wkG);
            int kb = half * 16;
            #pragma unroll 8
            for (int k4 = 0; k4 < 16; ++k4) {
                float4 xv = x4[row * 32 + kb + k4];
                float4 wa = wa4[kb + k4], wg = wg4[kb + k4];
                sA = fmaf(xv.x, wa.x, fmaf(xv.y, wa.y, fmaf(xv.z, wa.z, fmaf(xv.w, wa.w, sA))));
                sG = fmaf(xv.x, wg.x, fmaf(xv.y, wg.y, fmaf(xv.z, wg.z, fmaf(xv.w, wg.w, sG))));
            }
        }
        sPk[half][unit] = make_float2(sA, sG);
    }
    __syncthreads();

    // combine pack halves and store (first 256 threads)
    if (tid < 256) {
        int r = tid & 127, h = tid >> 7;
        int row = rowBase + r;
        if (row < n_nodes) {
            float2 a = sPk[0][tid], b = sPk[1][tid];
            float2 res = make_float2(a.x + b.x, a.y + b.y);
            if (h) dstPack[row] = res;
            else   srcPack[row] = res;
        }
    }

    const int wave = tid >> 6, lane = tid & 63;
    const int ln = lane & 15, quad = lane >> 4;
    const int wm = (wave & 3) * 32, wn = (wave >> 2) * 64;

    f32x4 acc[2][4];
    #pragma unroll
    for (int i = 0; i < 2; ++i)
        #pragma unroll
        for (int j = 0; j < 4; ++j) acc[i][j] = (f32x4){0.f, 0.f, 0.f, 0.f};

    #pragma unroll
    for (int kc = 0; kc < 4; ++kc) {
        int k0 = kc * 32 + quad * 8;
        bf16x8 afr[2], bfr[4];
        #pragma unroll
        for (int mt = 0; mt < 2; ++mt)
            afr[mt] = *(const bf16x8*)&Asu[wm + mt * 16 + ln][k0];
        #pragma unroll
        for (int nt = 0; nt < 4; ++nt)
            bfr[nt] = *(const bf16x8*)&Bsu[wn + nt * 16 + ln][k0];
        #pragma unroll
        for (int mt = 0; mt < 2; ++mt)
            #pragma unroll
            for (int nt = 0; nt < 4; ++nt)
                acc[mt][nt] = __builtin_amdgcn_mfma_f32_16x16x32_bf16(
                    afr[mt], bfr[nt], acc[mt][nt], 0, 0, 0);
    }

    // epilogue: D col = ln, row = quad*4 + reg; pack col pairs via shfl_xor(1)
    #pragma unroll
    for (int nt = 0; nt < 4; ++nt) {
        int col = wn + nt * 16 + ln;
        float cb = c2[col];
        #pragma unroll
        for (int mt = 0; mt < 2; ++mt) {
            #pragma unroll
            for (int r = 0; r < 4; ++r) {
                int row = rowBase + wm + mt * 16 + quad * 4 + r;
                float v = acc[mt][nt][r] + cb;
                float pv = __shfl_xor(v, 1, 64);
                if (!(ln & 1) && row < n_nodes) {
                    Vmb[row * 64 + (col >> 1)] = bf16rne(v) | (bf16rne(pv) << 16);
                }
            }
        }
    }
}

// edge1a: rule-MLP (8 edges/thread) + dst>>8 histogram fused.
__global__ void __launch_bounds__(256) edge1a_kernel(
    const float4* __restrict__ erf, const int* __restrict__ dsts,
    const float4* __restrict__ w1t, const float2* __restrict__ w12,
    const float* __restrict__ rule_b2,
    float* __restrict__ b_out, int* __restrict__ hpart, int n_edges)
{
    __shared__ float4 s_w1t[128];
    __shared__ float2 s_w12[128];
    __shared__ int cnt[256];
    const int tid = threadIdx.x;
    if (tid < 128) { s_w1t[tid] = w1t[tid]; s_w12[tid] = w12[tid]; }
    cnt[tid] = 0;
    __syncthreads();

    const int eb = blockIdx.x * 2048;
    float4 rf[8];
    #pragma unroll
    for (int q = 0; q < 8; ++q) {
        int e = eb + q * 256 + tid;
        rf[q] = erf[min(e, n_edges - 1)];
        if (e < n_edges) atomicAdd(&cnt[dsts[e] >> 8], 1);
    }

    float bacc[8] = {0.f, 0.f, 0.f, 0.f, 0.f, 0.f, 0.f, 0.f};
    #pragma unroll 2
    for (int j = 0; j < 128; ++j) {
        float4 w = s_w1t[j];
        float2 c = s_w12[j];
        #pragma unroll
        for (int q = 0; q < 8; ++q) {
            float h = fmaf(rf[q].x, w.x, fmaf(rf[q].y, w.y,
                      fmaf(rf[q].z, w.z, fmaf(rf[q].w, w.w, c.x))));
            bacc[q] = fmaf(fmaxf(h, 0.f), c.y, bacc[q]);
        }
    }

    const float rb2 = rule_b2[0];
    #pragma unroll
    for (int q = 0; q < 8; ++q) {
        int e = eb + q * 256 + tid;
        if (e < n_edges) b_out[e] = bacc[q] + rb2;
    }
    __syncthreads();
    hpart[blockIdx.x * 256 + tid] = cnt[tid];
}

// hred: 256 blocks; block b reduces hpart column b (nblk entries) in parallel.
__global__ void __launch_bounds__(256) hred_kernel(
    const int* __restrict__ hpart, int* __restrict__ bucketTotal, int nblk)
{
    __shared__ int sdata[256];
    const int tid = threadIdx.x;
    const int b = blockIdx.x;
    int s = 0;
    for (int i = tid; i < nblk; i += 256) s += hpart[i * 256 + b];
    sdata[tid] = s;
    __syncthreads();
    #pragma unroll
    for (int off2 = 128; off2 > 0; off2 >>= 1) {
        if (tid < off2) sdata[tid] += sdata[tid + off2];
        __syncthreads();
    }
    if (tid == 0) bucketTotal[b] = sdata[0];
}

// hscan: single block scans the 256 bucket totals -> bucketCursor (mutable,
// for sort1) + bucketStart (read-only, for sort2) + rowPtr[n_nodes].
__global__ void __launch_bounds__(256) hscan_kernel(
    const int* __restrict__ bucketTotal, int* __restrict__ bucketCursor,
    int* __restrict__ bucketStart, int* __restrict__ rowPtr,
    int n_nodes, int n_edges)
{
    __shared__ int sdata[256];
    const int tid = threadIdx.x;
    int s = bucketTotal[tid];
    sdata[tid] = s;
    __syncthreads();
    #pragma unroll
    for (int off = 1; off < 256; off <<= 1) {
        int t = (tid >= off) ? sdata[tid - off] : 0;
        __syncthreads();
        sdata[tid] += t;
        __syncthreads();
    }
    int excl = sdata[tid] - s;
    bucketCursor[tid] = excl;
    bucketStart[tid] = excl;
    if (tid == 0) rowPtr[n_nodes] = n_edges;
}

// sort1 (fused with edge tail): per edge compute gamma/e_val in-register,
// store both coalesced, then LDS-binned coarse scatter into bucket regions
// (bucket = dst >> 8) with coalesced run copy. (R16 form.)
__global__ void __launch_bounds__(256) sort1_kernel(
    const int* __restrict__ ei, const int* __restrict__ et,
    const float4* __restrict__ erf, const float* __restrict__ b_out,
    const float* __restrict__ grw,
    const float2* __restrict__ srcPack, const float2* __restrict__ dstPack,
    const float* __restrict__ relA, const float* __restrict__ consts,
    float* __restrict__ e_val, float* __restrict__ gamma_out,
    int* __restrict__ bucketCursor, float2* __restrict__ tmp, int n_edges)
{
    __shared__ float2 data[4096];          // 32 KB
    __shared__ unsigned char slotB[4096];  // 4 KB
    __shared__ int cnt[256], rk[256], base_[256], run[256], scanBuf[256];
    __shared__ float s_relA[16];
    const int tid = threadIdx.x;
    const int blockBase = blockIdx.x * 4096;
    const int total = min(4096, n_edges - blockBase);

    cnt[tid] = 0;
    rk[tid] = 0;
    if (tid < 16) s_relA[tid] = relA[tid];
    __syncthreads();

    const float c0 = consts[0], c1 = consts[1];
    const float g0 = grw[0], g1 = grw[1], g2 = grw[2], g3 = grw[3];

    int   d_[16];
    float ev_[16];
    int   pk_[16];
    #pragma unroll
    for (int i = 0; i < 16; ++i) {
        int e = blockBase + i * 256 + tid;
        if (e < n_edges) {
            int s = ei[e];
            int d = ei[n_edges + e];
            int t = et[e];
            float4 rf = erf[e];
            float b = b_out[e];
            float2 ss = srcPack[s], dd = dstPack[d];
            float pre = ss.x + dd.x + s_relA[t] + c0;
            float e_base = pre >= 0.f ? pre : 0.2f * pre;
            float gl = fmaf(rf.x, g0, fmaf(rf.y, g1,
                       fmaf(rf.z, g2, fmaf(rf.w, g3, c1 + ss.y + dd.y))));
            float gamma = 1.f / (1.f + __expf(-gl));
            float ev = e_base + gamma * b;
            gamma_out[e] = gamma;
            e_val[e] = ev;
            d_[i]  = d;
            ev_[i] = ev;
            pk_[i] = (s & 0xFFFF) | ((t & 15) << 16) | ((d & 255) << 20);
            atomicAdd(&cnt[d >> 8], 1);
        } else {
            d_[i] = -1;
        }
    }
    __syncthreads();

    int c = cnt[tid];
    scanBuf[tid] = c;
    __syncthreads();
    #pragma unroll
    for (int off = 1; off < 256; off <<= 1) {
        int t = (tid >= off) ? scanBuf[tid - off] : 0;
        __syncthreads();
        scanBuf[tid] += t;
        __syncthreads();
    }
    base_[tid] = scanBuf[tid] - c;
    run[tid] = c ? atomicAdd(&bucketCursor[tid], c) : 0;
    __syncthreads();

    #pragma unroll
    for (int i = 0; i < 16; ++i) {
        if (d_[i] >= 0) {
            int b = d_[i] >> 8;
            int r = atomicAdd(&rk[b], 1);
            int slot = base_[b] + r;
            data[slot] = make_float2(ev_[i], __int_as_float(pk_[i]));
            slotB[slot] = (unsigned char)b;
        }
    }
    __syncthreads();

    for (int j = tid; j < total; j += 256) {
        int b = slotB[j];
        tmp[run[b] + (j - base_[b])] = data[j];
    }
}

// sort2: per-bucket exact CSR placement, two-pass (R16 form): histogram
// pass over tmp, local scan (writes rowPtr), placement pass re-reads tmp.
__global__ void __launch_bounds__(256) sort2_kernel(
    const int* __restrict__ bucketStart, const float2* __restrict__ tmp,
    float2* __restrict__ payload, int* __restrict__ rowPtr,
    int n_nodes, int n_edges, int nbuck)
{
    __shared__ int cnt[256], cur[256], sdata[256];
    const int tid = threadIdx.x;
    const int b = blockIdx.x;
    const int d0 = b * 256;
    const int lo = bucketStart[b];
    const int hi = (b == nbuck - 1) ? n_edges : bucketStart[b + 1];

    cnt[tid] = 0;
    __syncthreads();
    for (int j = lo + tid; j < hi; j += 256) {
        unsigned pk = __float_as_uint(tmp[j].y);
        atomicAdd(&cnt[(pk >> 20) & 255], 1);
    }
    __syncthreads();

    int c = cnt[tid];
    sdata[tid] = c;
    __syncthreads();
    #pragma unroll
    for (int off = 1; off < 256; off <<= 1) {
        int t = (tid >= off) ? sdata[tid - off] : 0;
        __syncthreads();
        sdata[tid] += t;
        __syncthreads();
    }
    int excl = sdata[tid] - c;
    cur[tid] = lo + excl;
    if (d0 + tid < n_nodes) rowPtr[d0 + tid] = lo + excl;
    __syncthreads();

    for (int j = lo + tid; j < hi; j += 256) {
        float2 p = tmp[j];
        unsigned pk = __float_as_uint(p.y);
        int dl = (pk >> 20) & 255;
        int pos = atomicAdd(&cur[dl], 1);
        unsigned st = (pk & 0xFFFFu) | (((pk >> 16) & 15u) << 27);
        payload[pos] = make_float2(p.x, __uint_as_float(st));
    }
}

// one wave per dst node, pair-processed: lanes 0-31 own even-offset edges,
// lanes 32-63 odd-offset edges; each lane reads uint2 of Vmb (4 dims).
// Per 16 edges: 8 VMEM + 8 LDS reads (was 16+16). relM epilogue splits
// types 0-7 / 8-15 across halves; shfl_xor(32) combines; float4 out write.
__global__ void __launch_bounds__(256) gather_kernel(
    const int* __restrict__ rowPtr, const float2* __restrict__ payload,
    const uint2* __restrict__ Vmb2, const float* __restrict__ relM,
    float* __restrict__ out, float2* __restrict__ nodeMS, int n_nodes)
{
    __shared__ float4 s_relM4[16 * 32];  // 8 KB: relM as float4[type][c]
    __shared__ float2 s_pay[4][64];      // 2 KB: per-wave (av, st) staging
    __shared__ float  s_ts[4][16];       // per-wave per-type alpha sums
    const int tid = threadIdx.x;
    const float4* relM4 = (const float4*)relM;
    s_relM4[tid] = relM4[tid];
    s_relM4[256 + tid] = relM4[256 + tid];

    const int lane = tid & 63;
    const int w = tid >> 6;
    const int h = lane >> 5;    // edge-parity half
    const int c = lane & 31;    // dim-group (4 dims: 4c..4c+3)
    if (lane < 16) s_ts[w][lane] = 0.f;
    __syncthreads();

    int d = blockIdx.x * 4 + w;
    if (d >= n_nodes) return;
    int start = rowPtr[d];
    int deg = rowPtr[d + 1] - start;

    float a0 = 0.f, a1 = 0.f, a2 = 0.f, a3 = 0.f;
    float m = -INFINITY, inv;

    // consume s_pay[w][0..cnt): 8 edge-pairs (16 edges) per iteration
    auto accrun = [&](int cnt) {
        for (int k = 0; k < cnt; k += 16) {
            float a[8];
            int ss[8];
            #pragma unroll
            for (int i = 0; i < 8; ++i) {
                float2 p = s_pay[w][k + 2 * i + h];  // 2-addr broadcast
                a[i]  = p.x;
                ss[i] = __float_as_int(p.y) & 0x7FFFFFF;
            }
            uint2 v[8];
            #pragma unroll
            for (int i = 0; i < 8; ++i) v[i] = Vmb2[ss[i] * 32 + c];
            #pragma unroll
            for (int i = 0; i < 8; ++i) {
                a0 = fmaf(a[i], bflo(v[i].x), a0);
                a1 = fmaf(a[i], bfhi(v[i].x), a1);
                a2 = fmaf(a[i], bflo(v[i].y), a2);
                a3 = fmaf(a[i], bfhi(v[i].y), a3);
            }
        }
    };

    if (deg <= 64) {
        float ev = -INFINITY;
        int st = 0;
        if (lane < deg) {
            float2 p = payload[start + lane];
            ev = p.x;
            st = __float_as_int(p.y);
        }
        m = wave_max(ev);
        float ex = (lane < deg) ? __expf(ev - m) : 0.f;
        float sum = wave_sum(ex);
        inv = 1.f / (sum + 1e-16f);
        float av = ex * inv;
        s_pay[w][lane] = make_float2(av, __int_as_float(st));
        if (lane < deg) atomicAdd(&s_ts[w][((unsigned)st) >> 27], av);
        accrun(deg);
    } else {
        for (int i = lane; i < deg; i += 64) m = fmaxf(m, payload[start + i].x);
        m = wave_max(m);
        float sum = 0.f;
        for (int i = lane; i < deg; i += 64) sum += __expf(payload[start + i].x - m);
        sum = wave_sum(sum);
        inv = 1.f / (sum + 1e-16f);
        for (int cc = 0; cc < deg; cc += 64) {
            int i = cc + lane;
            float av = 0.f;
            int st = 0;
            if (i < deg) {
                float2 p = payload[start + i];
                av = __expf(p.x - m) * inv;
                st = __float_as_int(p.y);
            }
            s_pay[w][lane] = make_float2(av, __int_as_float(st));
            if (i < deg) atomicAdd(&s_ts[w][((unsigned)st) >> 27], av);
            accrun(min(64, deg - cc));
        }
    }

    // epilogue: per-type relM contribution (types split across halves)
    const int tbase = h * 8;
    #pragma unroll
    for (int t = 0; t < 8; ++t) {
        float ts = s_ts[w][tbase + t];
        float4 rm = s_relM4[(tbase + t) * 32 + c];
        a0 = fmaf(ts, rm.x, a0);
        a1 = fmaf(ts, rm.y, a1);
        a2 = fmaf(ts, rm.z, a2);
        a3 = fmaf(ts, rm.w, a3);
    }
    // combine halves (lane c and c+32 hold the same dims)
    a0 += __shfl_xor(a0, 32, 64);
    a1 += __shfl_xor(a1, 32, 64);
    a2 += __shfl_xor(a2, 32, 64);
    a3 += __shfl_xor(a3, 32, 64);

    if (lane == 0) nodeMS[d] = make_float2(m, inv);
    if (h == 0)
        *(float4*)&out[d * 128 + c * 4] = make_float4(a0, a1, a2, a3);
}

// fully-coalesced alpha: alpha[e] = exp(e_val[e] - m[d]) * inv[d]
__global__ void __launch_bounds__(256) alpha_kernel(
    const int* __restrict__ ei, const float* __restrict__ e_val,
    const float2* __restrict__ nodeMS, float* __restrict__ alpha_out, int n_edges)
{
    int e = blockIdx.x * blockDim.x + threadIdx.x;
    if (e >= n_edges) return;
    int d = ei[n_edges + e];
    float2 ms = nodeMS[d];
    alpha_out[e] = __expf(e_val[e] - ms.x) * ms.y;
}

extern "C" void kernel_launch(void* const* d_in, const int* in_sizes, int n_in,
                              void* d_out, int out_size, void* d_ws, size_t ws_size,
                              hipStream_t stream)
{
    const float* x        = (const float*)d_in[0];
    const int*   ei       = (const int*)d_in[1];
    const int*   et       = (const int*)d_in[2];
    const float* erf      = (const float*)d_in[3];
    const float* Wq       = (const float*)d_in[5];
    const float* bq       = (const float*)d_in[6];
    const float* Wk       = (const float*)d_in[7];
    const float* bk       = (const float*)d_in[8];
    const float* Wv       = (const float*)d_in[9];
    const float* bv       = (const float*)d_in[10];
    const float* rel_emb  = (const float*)d_in[11];
    const float* attn_vec = (const float*)d_in[12];
    const float* rule_w1  = (const float*)d_in[13];
    const float* rule_b1  = (const float*)d_in[14];
    const float* rule_w2  = (const float*)d_in[15];
    const float* rule_b2  = (const float*)d_in[16];
    const float* grw      = (const float*)d_in[17];
    const float* grb      = (const float*)d_in[18];
    const float* gnw      = (const float*)d_in[19];
    const float* gnb      = (const float*)d_in[20];
    const float* msg_w    = (const float*)d_in[21];
    const float* msg_b    = (const float*)d_in[22];

    const int n_nodes = in_sizes[0] / 128;
    const int n_edges = in_sizes[2];
    const int nab = (n_edges + 2047) / 2048;  // edge1a blocks (hpart rows)
    const int nhb = (n_edges + 4095) / 4096;  // sort1 blocks
    const int nbuck = (n_nodes + 255) / 256;  // coarse buckets (<= 256)

    float* ws = (float*)d_ws;
    size_t off = 0;
    unsigned* Vmb  = (unsigned*)(ws + off); off += (size_t)n_nodes * 64;
    float2* payload = (float2*)(ws + off); off += 2 * (size_t)n_edges;
    float2* tmpPay  = (float2*)(ws + off); off += 2 * (size_t)n_edges;
    float* e_val   = ws + off; off += n_edges;
    float* srcPack = ws + off; off += 2 * (size_t)n_nodes;
    float* dstPack = ws + off; off += 2 * (size_t)n_nodes;
    float2* nodeMS = (float2*)(ws + off); off += 2 * (size_t)n_nodes;
    int*   rowPtr  = (int*)(ws + off); off += n_nodes + 4;
    int*   hpart   = (int*)(ws + off); off += (size_t)nab * 256;
    int*   bucketCursor = (int*)(ws + off); off += 256;
    int*   bucketStart  = (int*)(ws + off); off += 256;
    int*   bucketTotal  = (int*)(ws + off); off += 256;
    unsigned short* W2bT = (unsigned short*)(ws + off); off += 128 * 64;
    float* c2      = ws + off; off += 128;
    float* wkA     = ws + off; off += 128;
    float* wqA     = ws + off; off += 128;
    float* wkG     = ws + off; off += 128;
    float* wqG     = ws + off; off += 128;
    float* relA    = ws + off; off += 16;
    float* relM    = ws + off; off += 16 * 128;
    float* consts  = ws + off; off += 2;
    off += 2;  // 16B alignment for w1t
    float4* w1t    = (float4*)(ws + off); off += 128 * 4;
    float2* w12    = (float2*)(ws + off); off += 128 * 2;

    float* out       = (float*)d_out;
    float* alpha_out = out + (size_t)n_nodes * 128;
    float* gamma_out = alpha_out + n_edges;
    float* b_out     = gamma_out + n_edges;

    hipLaunchKernelGGL(precompute_kernel, dim3(146), dim3(128), 0, stream,
                       Wq, bq, Wk, bk, Wv, bv, rel_emb, attn_vec, msg_w, msg_b,
                       gnw, grb, gnb, rule_w1, rule_b1, rule_w2,
                       W2bT, c2, wkA, wqA, wkG, wqG, relA, relM, consts, w1t, w12);

    hipLaunchKernelGGL(node_kernel, dim3((n_nodes + 127) / 128), dim3(512), 0, stream,
                       (const float4*)x, W2bT, c2,
                       wkA, wqA, wkG, wqG, Vmb, (float2*)srcPack, (float2*)dstPack,
                       n_nodes);

    hipLaunchKernelGGL(edge1a_kernel, dim3(nab), dim3(256), 0, stream,
                       (const float4*)erf, ei + n_edges,
                       (const float4*)w1t, (const float2*)w12,
                       rule_b2, b_out, hpart, n_edges);

    hipLaunchKernelGGL(hred_kernel, dim3(256), dim3(256), 0, stream,
                       hpart, bucketTotal, nab);

    hipLaunchKernelGGL(hscan_kernel, dim3(1), dim3(256), 0, stream,
                       bucketTotal, bucketCursor, bucketStart, rowPtr,
                       n_nodes, n_edges);

    hipLaunchKernelGGL(sort1_kernel, dim3(nhb), dim3(256), 0, stream,
                       ei, et, (const float4*)erf, b_out, grw,
                       (const float2*)srcPack, (const float2*)dstPack,
                       relA, consts, e_val, gamma_out,
                       bucketCursor, tmpPay, n_edges);

    hipLaunchKernelGGL(sort2_kernel, dim3(nbuck), dim3(256), 0, stream,
                       bucketStart, tmpPay, payload, rowPtr,
                       n_nodes, n_edges, nbuck);

    hipLaunchKernelGGL(gather_kernel, dim3((n_nodes + 3) / 4), dim3(256), 0, stream,
                       rowPtr, payload, (const uint2*)Vmb, relM, out, nodeMS, n_nodes);

    hipLaunchKernelGGL(alpha_kernel, dim3((n_edges + 255) / 256), dim3(256), 0, stream,
                       ei, e_val, nodeMS, alpha_out, n_edges);
}